// Round 8
// baseline (247.681 us; speedup 1.0000x reference)
//
#include <hip/hip_runtime.h>
#include <hip/hip_bf16.h>
#include <stdint.h>

// Problem constants: B=2, N=2048, D=1024, H=16, head dim s=64.
// Global I/O fp32; internal X/W/Q/K/V/Y intermediates bf16 in d_ws.
// Q is pre-scaled by 0.125*log2e so attention softmax runs in exp2 domain.
#define BB 2
#define NN 2048
#define DD 1024
#define HH 16
#define SS 64

typedef short short8 __attribute__((ext_vector_type(8)));
typedef float f32x4 __attribute__((ext_vector_type(4)));

__device__ __forceinline__ float bf2f(uint16_t u) {
    return __uint_as_float(((uint32_t)u) << 16);
}
__device__ __forceinline__ uint16_t f2bf(float f) {
    uint32_t u = __float_as_uint(f);
    return (uint16_t)((u + 0x7FFFu + ((u >> 16) & 1u)) >> 16);  // RNE
}
__device__ __forceinline__ short8 cvt8(float4 a, float4 b) {
    short8 s;
    s[0] = (short)f2bf(a.x); s[1] = (short)f2bf(a.y);
    s[2] = (short)f2bf(a.z); s[3] = (short)f2bf(a.w);
    s[4] = (short)f2bf(b.x); s[5] = (short)f2bf(b.y);
    s[6] = (short)f2bf(b.z); s[7] = (short)f2bf(b.w);
    return s;
}

__device__ __forceinline__ void load_lds16(const uint16_t* g, uint16_t* l) {
    __builtin_amdgcn_global_load_lds(
        (const __attribute__((address_space(1))) void*)g,
        (__attribute__((address_space(3))) void*)l, 16, 0, 0);
}

// ======================= fp32 -> bf16 bulk convert =======================
__global__ __launch_bounds__(256) void cvt_bf16(
    const float* __restrict__ src, uint16_t* __restrict__ dst, int n)
{
    int i = (blockIdx.x * 256 + threadIdx.x) * 8;
    if (i >= n) return;
    float4 a = *(const float4*)(src + i);
    float4 b = *(const float4*)(src + i + 4);
    *(short8*)(dst + i) = cvt8(a, b);
}

// ======================= QKV projection (MFMA, bf16 in) =======================
// C[4096,3072] = X[4096,1024] @ Wqkv[3072,1024]^T + bqkv
// -> Q bf16 (x0.125*log2e) [bh][2048][64], K bf16 [bh][2048][64], V^T [bh][64][2048]
__global__ __launch_bounds__(256) void gemm_qkv(
    const uint16_t* __restrict__ X, const uint16_t* __restrict__ W,
    const float* __restrict__ bias,
    uint16_t* __restrict__ Qb, uint16_t* __restrict__ Kb, uint16_t* __restrict__ Vt)
{
    __shared__ __align__(16) uint16_t smem[18432];   // 36,864 B
    uint16_t* As = smem;          // [128][32] linear (gload_lds requires)
    uint16_t* Bs = smem + 4096;   // [128][32]

    const int tid = threadIdx.x;
    const int w = tid >> 6, l = tid & 63;
    const int lq = l & 15, lg = l >> 4;
    const int wm = w >> 1, wn = w & 1;
    const int m0 = blockIdx.y * 128;
    const int n0 = blockIdx.x * 128;

    f32x4 acc[4][4] = {};

    for (int k0 = 0; k0 < 1024; k0 += 32) {
        __syncthreads();
        #pragma unroll
        for (int j = 0; j < 2; ++j) {
            const int c = (j * 4 + w) * 64 + l;   // lane's global row/col chunk
            load_lds16(X + (size_t)(m0 + (c >> 2)) * 1024 + k0 + (c & 3) * 8,
                       As + (j * 4 + w) * 512);
            load_lds16(W + (size_t)(n0 + (c >> 2)) * 1024 + k0 + (c & 3) * 8,
                       Bs + (j * 4 + w) * 512);
        }
        __syncthreads();
        short8 af[4], bfr[4];
        #pragma unroll
        for (int mi = 0; mi < 4; ++mi)
            af[mi] = *(const short8*)&As[(wm * 64 + mi * 16 + lq) * 32 + lg * 8];
        #pragma unroll
        for (int ni = 0; ni < 4; ++ni)
            bfr[ni] = *(const short8*)&Bs[(wn * 64 + ni * 16 + lq) * 32 + lg * 8];
        #pragma unroll
        for (int mi = 0; mi < 4; ++mi)
            #pragma unroll
            for (int ni = 0; ni < 4; ++ni)
                acc[mi][ni] = __builtin_amdgcn_mfma_f32_16x16x32_bf16(
                    af[mi], bfr[ni], acc[mi][ni], 0, 0, 0);
    }

    // ---------------- epilogue: bf16 scatter via LDS transpose ----------------
    __syncthreads();  // staging reads complete; reuse smem
    const int part = n0 >> 10;                       // 0=Q 1=K 2=V (uniform)
    const int hh = ((n0 + wn * 64) & 1023) >> 6;     // head (uniform per wave)
    const int mrow0 = m0 + wm * 64;
    const int bh = (mrow0 >> 11) * 16 + hh;
    const int tok0 = mrow0 & 2047;
    // Q pre-scale folds 1/sqrt(64) and log2e for exp2-domain softmax.
    const float scl = (part == 0) ? 0.125f * 1.44269504089f : 1.0f;

    float bias4[4];
    #pragma unroll
    for (int ni = 0; ni < 4; ++ni)
        bias4[ni] = bias[n0 + wn * 64 + ni * 16 + lq];

    uint16_t* T = smem + w * 4608;                   // [64][72] bf16, wave-private
    if (part < 2) {
        #pragma unroll
        for (int mi = 0; mi < 4; ++mi)
            #pragma unroll
            for (int ni = 0; ni < 4; ++ni)
                #pragma unroll
                for (int r = 0; r < 4; ++r)
                    T[(mi * 16 + lg * 4 + r) * 72 + ni * 16 + lq] =
                        f2bf((acc[mi][ni][r] + bias4[ni]) * scl);
    } else {
        #pragma unroll
        for (int mi = 0; mi < 4; ++mi)
            #pragma unroll
            for (int ni = 0; ni < 4; ++ni)
                #pragma unroll
                for (int r = 0; r < 4; ++r)
                    T[(ni * 16 + lq) * 72 + mi * 16 + lg * 4 + r] =
                        f2bf(acc[mi][ni][r] + bias4[ni]);
    }

    const int a0 = l >> 3, b8 = (l & 7) * 8;
    #pragma unroll
    for (int i = 0; i < 8; ++i) {
        int a = i * 8 + a0;
        short8 u = *(short8*)&T[a * 72 + b8];
        uint16_t* p;
        if (part < 2) {
            uint16_t* dst = (part == 0) ? Qb : Kb;
            p = dst + ((size_t)bh * 2048 + tok0 + a) * 64 + b8;
        } else {
            p = Vt + ((size_t)bh * 64 + a) * 2048 + tok0 + b8;
        }
        *(short8*)p = u;
    }
}

// ======================= MFMA flash attention (1-wave blocks) =======================
// 4096 blocks x 64 thr. Block id: bh = id&31 (id%8 -> XCD affinity for K/V L2),
// strip rank = id>>5 descending work (strip = 127-rank). Single-buffered K/V
// fragments (K(t+1) issued after QK(t) consumes; covered by softmax+PV).
// Defer-max (T13) skips y-rescale when max growth <= THR. exp2-domain softmax.
__device__ __forceinline__ void loadKf(const uint16_t* Kb, int kv0, int lq, int lg,
                                       short8 (&d)[8]) {
    #pragma unroll
    for (int n = 0; n < 4; ++n) {
        const uint16_t* kb = Kb + (size_t)(kv0 + n * 16 + lq) * 64 + lg * 8;
        d[2 * n]     = *(const short8*)kb;
        d[2 * n + 1] = *(const short8*)(kb + 32);
    }
}
__device__ __forceinline__ void loadVf(const uint16_t* Vb, int kv0, int lq, int lg,
                                       short8 (&d)[8]) {
    #pragma unroll
    for (int n = 0; n < 4; ++n) {
        const uint16_t* vb = Vb + (size_t)(n * 16 + lq) * 2048 + kv0 + lg * 8;
        d[2 * n]     = *(const short8*)vb;
        d[2 * n + 1] = *(const short8*)(vb + 32);
    }
}

#define DEFER_THR 11.5f   // 8 nats in log2 units

__global__ __launch_bounds__(64, 4) void attn_mfma(
    const uint16_t* __restrict__ Q, const uint16_t* __restrict__ K,
    const uint16_t* __restrict__ Vt, uint16_t* __restrict__ Y)
{
    const int id = blockIdx.x;
    const int bh = id & 31;               // id%8 -> stable XCD per bh group
    const int strip = 127 - (id >> 5);    // descending work
    const int qt = strip >> 2;            // last kv tile index
    const int q0 = strip * 16;

    const int lane = threadIdx.x;
    const int lq = lane & 15;
    const int lg = lane >> 4;

    __shared__ __align__(16) uint16_t Pl[16][72];

    const uint16_t* Kb = K + (size_t)bh * (2048 * 64);
    const uint16_t* Vb = Vt + (size_t)bh * (64 * 2048);
    const int b = bh >> 4, h = bh & 15;

    const uint16_t* qbase = Q + ((size_t)bh * 2048 + q0 + lq) * 64 + lg * 8;
    short8 qf0 = *(const short8*)qbase;
    short8 qf1 = *(const short8*)(qbase + 32);

    f32x4 y[4] = {};
    float m[4], lsum[4];
    #pragma unroll
    for (int r = 0; r < 4; ++r) { m[r] = -INFINITY; lsum[r] = 0.f; }

    short8 kf[8], vv[8];
    loadKf(Kb, 0, lq, lg, kf);
    loadVf(Vb, 0, lq, lg, vv);

    for (int kt = 0; kt <= qt; ++kt) {
        const int kv0 = kt * 64;
        // ---- S = Q K^T (kf consumed here) ----
        f32x4 s[4];
        #pragma unroll
        for (int n = 0; n < 4; ++n) {
            f32x4 z = {};
            z = __builtin_amdgcn_mfma_f32_16x16x32_bf16(qf0, kf[2 * n], z, 0, 0, 0);
            s[n] = __builtin_amdgcn_mfma_f32_16x16x32_bf16(qf1, kf[2 * n + 1], z, 0, 0, 0);
        }
        // refill K for next tile (latency hidden under softmax+PV)
        if (kt < qt) loadKf(Kb, kv0 + 64, lq, lg, kf);

        if (kt == qt) {
            const int rowb = q0 + lg * 4;
            #pragma unroll
            for (int n = 0; n < 4; ++n) {
                int col = kv0 + n * 16 + lq;
                #pragma unroll
                for (int r = 0; r < 4; ++r)
                    if (col > rowb + r) s[n][r] = -INFINITY;
            }
        }
        // ---- online softmax (exp2 domain, defer-max) ----
        float mt[4];
        #pragma unroll
        for (int r = 0; r < 4; ++r)
            mt[r] = fmaxf(fmaxf(s[0][r], s[1][r]), fmaxf(s[2][r], s[3][r]));
        #pragma unroll
        for (int off = 1; off <= 8; off <<= 1)
            #pragma unroll
            for (int r = 0; r < 4; ++r)
                mt[r] = fmaxf(mt[r], __shfl_xor(mt[r], off));

        float g = -INFINITY;
        #pragma unroll
        for (int r = 0; r < 4; ++r) g = fmaxf(g, mt[r] - m[r]);
        const bool skip = __all(g <= DEFER_THR);

        float sc[4];
        if (!skip) {
            #pragma unroll
            for (int r = 0; r < 4; ++r) {
                float mn = fmaxf(m[r], mt[r]);
                sc[r] = exp2f(m[r] - mn);
                m[r] = mn;
            }
        }

        float psum[4] = {0.f, 0.f, 0.f, 0.f};
        #pragma unroll
        for (int n = 0; n < 4; ++n)
            #pragma unroll
            for (int r = 0; r < 4; ++r) {
                float p = exp2f(s[n][r] - m[r]);
                psum[r] += p;
                Pl[lg * 4 + r][n * 16 + lq] = f2bf(p);
            }
        #pragma unroll
        for (int off = 1; off <= 8; off <<= 1)
            #pragma unroll
            for (int r = 0; r < 4; ++r)
                psum[r] += __shfl_xor(psum[r], off);

        if (skip) {
            #pragma unroll
            for (int r = 0; r < 4; ++r) lsum[r] += psum[r];
        } else {
            #pragma unroll
            for (int r = 0; r < 4; ++r) lsum[r] = lsum[r] * sc[r] + psum[r];
            #pragma unroll
            for (int n = 0; n < 4; ++n)
                #pragma unroll
                for (int r = 0; r < 4; ++r)
                    y[n][r] *= sc[r];
        }

        // ---- P fragments via wave-private LDS ----
        short8 pa0 = *(short8*)&Pl[lq][lg * 8];
        short8 pa1 = *(short8*)&Pl[lq][lg * 8 + 32];
        // ---- Y += P V (vv consumed here) ----
        #pragma unroll
        for (int n = 0; n < 4; ++n) {
            y[n] = __builtin_amdgcn_mfma_f32_16x16x32_bf16(pa0, vv[2 * n], y[n], 0, 0, 0);
            y[n] = __builtin_amdgcn_mfma_f32_16x16x32_bf16(pa1, vv[2 * n + 1], y[n], 0, 0, 0);
        }
        // refill V for next tile
        if (kt < qt) loadVf(Vb, kv0 + 64, lq, lg, vv);
    }

    #pragma unroll
    for (int r = 0; r < 4; ++r) {
        float inv = 1.0f / lsum[r];
        int token = b * 2048 + q0 + lg * 4 + r;
        uint16_t* yrow = Y + (size_t)token * 1024 + h * 64;
        #pragma unroll
        for (int n = 0; n < 4; ++n)
            yrow[n * 16 + lq] = f2bf(y[n][r] * inv);
    }
}

// ======================= output projection (MFMA, fp32 out) =======================
// out[4096,1024] = Y(bf16) @ Wo(bf16)^T + bo
__global__ __launch_bounds__(256) void gemm_proj(
    const uint16_t* __restrict__ Yin, const uint16_t* __restrict__ W,
    const float* __restrict__ bias, float* __restrict__ out)
{
    __shared__ __align__(16) uint16_t smem[8192];   // 2 x [128][32]
    uint16_t* As = smem;
    uint16_t* Bs = smem + 4096;

    const int tid = threadIdx.x;
    const int w = tid >> 6, l = tid & 63;
    const int lq = l & 15, lg = l >> 4;
    const int wm = w >> 1, wn = w & 1;
    const int m0 = blockIdx.y * 128;
    const int n0 = blockIdx.x * 128;

    f32x4 acc[4][4] = {};

    for (int k0 = 0; k0 < 1024; k0 += 32) {
        __syncthreads();
        #pragma unroll
        for (int j = 0; j < 2; ++j) {
            const int c = (j * 4 + w) * 64 + l;
            load_lds16(Yin + (size_t)(m0 + (c >> 2)) * 1024 + k0 + (c & 3) * 8,
                       As + (j * 4 + w) * 512);
            load_lds16(W + (size_t)(n0 + (c >> 2)) * 1024 + k0 + (c & 3) * 8,
                       Bs + (j * 4 + w) * 512);
        }
        __syncthreads();
        short8 af[4], bfr[4];
        #pragma unroll
        for (int mi = 0; mi < 4; ++mi)
            af[mi] = *(const short8*)&As[(wm * 64 + mi * 16 + lq) * 32 + lg * 8];
        #pragma unroll
        for (int ni = 0; ni < 4; ++ni)
            bfr[ni] = *(const short8*)&Bs[(wn * 64 + ni * 16 + lq) * 32 + lg * 8];
        #pragma unroll
        for (int mi = 0; mi < 4; ++mi)
            #pragma unroll
            for (int ni = 0; ni < 4; ++ni)
                acc[mi][ni] = __builtin_amdgcn_mfma_f32_16x16x32_bf16(
                    af[mi], bfr[ni], acc[mi][ni], 0, 0, 0);
    }

    // epilogue: direct fp32 stores from C-fragment layout
    const int mrow0 = m0 + wm * 64;
    const int ncol0 = n0 + wn * 64;
    float bias4[4];
    #pragma unroll
    for (int ni = 0; ni < 4; ++ni)
        bias4[ni] = bias[ncol0 + ni * 16 + lq];

    #pragma unroll
    for (int mi = 0; mi < 4; ++mi)
        #pragma unroll
        for (int r = 0; r < 4; ++r) {
            const size_t rowoff = (size_t)(mrow0 + mi * 16 + lg * 4 + r) * 1024;
            #pragma unroll
            for (int ni = 0; ni < 4; ++ni)
                out[rowoff + ncol0 + ni * 16 + lq] = acc[mi][ni][r] + bias4[ni];
        }
}

// ======================= launcher =======================

extern "C" void kernel_launch(void* const* d_in, const int* in_sizes, int n_in,
                              void* d_out, int out_size, void* d_ws, size_t ws_size,
                              hipStream_t stream) {
    const float* x    = (const float*)d_in[0];
    // d_in[1] (causal mask) applied structurally.
    const float* Wqkv = (const float*)d_in[2];
    const float* bqkv = (const float*)d_in[3];
    const float* Wo   = (const float*)d_in[4];
    const float* bo   = (const float*)d_in[5];

    const int XE  = 4096 * 1024;   // 4,194,304
    const int WQE = 3072 * 1024;   // 3,145,728
    const int WOE = 1024 * 1024;   // 1,048,576
    const size_t QK = (size_t)BB * HH * NN * SS;  // 4,194,304

    uint16_t* Xb  = (uint16_t*)d_ws;
    uint16_t* Wqb = Xb + XE;
    uint16_t* Wob = Wqb + WQE;
    uint16_t* Qb  = Wob + WOE;
    uint16_t* Kb  = Qb + QK;
    uint16_t* Vt  = Kb + QK;
    uint16_t* Yb  = Vt + QK;

    cvt_bf16<<<XE / 8 / 256, 256, 0, stream>>>(x, Xb, XE);
    cvt_bf16<<<WQE / 8 / 256, 256, 0, stream>>>(Wqkv, Wqb, WQE);
    cvt_bf16<<<WOE / 8 / 256, 256, 0, stream>>>(Wo, Wob, WOE);
    gemm_qkv<<<dim3(24, 32), 256, 0, stream>>>(Xb, Wqb, bqkv, Qb, Kb, Vt);
    attn_mfma<<<4096, 64, 0, stream>>>(Qb, Kb, Vt, Yb);
    gemm_proj<<<dim3(8, 32), 256, 0, stream>>>(Yb, Wob, bo, (float*)d_out);
}

// Round 9
// 231.572 us; speedup vs baseline: 1.0696x; 1.0696x over previous
//
#include <hip/hip_runtime.h>
#include <hip/hip_bf16.h>
#include <stdint.h>

// Problem constants: B=2, N=2048, D=1024, H=16, head dim s=64.
// Global I/O fp32; internal X/W/Q/K/V/Y intermediates bf16 in d_ws.
// Q is pre-scaled by 0.125*log2e so attention softmax runs in exp2 domain.
#define BB 2
#define NN 2048
#define DD 1024
#define HH 16
#define SS 64

typedef short short8 __attribute__((ext_vector_type(8)));
typedef float f32x4 __attribute__((ext_vector_type(4)));

__device__ __forceinline__ float bf2f(uint16_t u) {
    return __uint_as_float(((uint32_t)u) << 16);
}
__device__ __forceinline__ uint16_t f2bf(float f) {
    uint32_t u = __float_as_uint(f);
    return (uint16_t)((u + 0x7FFFu + ((u >> 16) & 1u)) >> 16);  // RNE
}
__device__ __forceinline__ short8 cvt8(float4 a, float4 b) {
    short8 s;
    s[0] = (short)f2bf(a.x); s[1] = (short)f2bf(a.y);
    s[2] = (short)f2bf(a.z); s[3] = (short)f2bf(a.w);
    s[4] = (short)f2bf(b.x); s[5] = (short)f2bf(b.y);
    s[6] = (short)f2bf(b.z); s[7] = (short)f2bf(b.w);
    return s;
}

__device__ __forceinline__ void load_lds16(const uint16_t* g, uint16_t* l) {
    __builtin_amdgcn_global_load_lds(
        (const __attribute__((address_space(1))) void*)g,
        (__attribute__((address_space(3))) void*)l, 16, 0, 0);
}

#define XE  (4096 * 1024)
#define WQE (3072 * 1024)
#define WOE (1024 * 1024)

// ======================= fused fp32 -> bf16 bulk convert =======================
// dst regions for x / Wqkv / Wo are contiguous in d_ws; one launch covers all.
__global__ __launch_bounds__(256) void cvt_all(
    const float* __restrict__ x, const float* __restrict__ wq,
    const float* __restrict__ wo, uint16_t* __restrict__ dst)
{
    int i = (blockIdx.x * 256 + threadIdx.x) * 8;
    const float* src;
    int off;
    if (i < XE)            { src = x;  off = i; }
    else if (i < XE + WQE) { src = wq; off = i - XE; }
    else                   { src = wo; off = i - XE - WQE; }
    float4 a = *(const float4*)(src + off);
    float4 b = *(const float4*)(src + off + 4);
    *(short8*)(dst + i) = cvt8(a, b);
}

// ======================= QKV projection (MFMA, bf16 in) =======================
// C[4096,3072] = X[4096,1024] @ Wqkv[3072,1024]^T + bqkv
// -> Q bf16 (x0.125*log2e) [bh][2048][64], K bf16 [bh][2048][64], V^T [bh][64][2048]
__global__ __launch_bounds__(256) void gemm_qkv(
    const uint16_t* __restrict__ X, const uint16_t* __restrict__ W,
    const float* __restrict__ bias,
    uint16_t* __restrict__ Qb, uint16_t* __restrict__ Kb, uint16_t* __restrict__ Vt)
{
    __shared__ __align__(16) uint16_t smem[18432];   // 36,864 B
    uint16_t* As = smem;          // [128][32] linear (gload_lds requires)
    uint16_t* Bs = smem + 4096;   // [128][32]

    const int tid = threadIdx.x;
    const int w = tid >> 6, l = tid & 63;
    const int lq = l & 15, lg = l >> 4;
    const int wm = w >> 1, wn = w & 1;
    const int m0 = blockIdx.y * 128;
    const int n0 = blockIdx.x * 128;

    f32x4 acc[4][4] = {};

    for (int k0 = 0; k0 < 1024; k0 += 32) {
        __syncthreads();
        #pragma unroll
        for (int j = 0; j < 2; ++j) {
            const int c = (j * 4 + w) * 64 + l;   // lane's global row/col chunk
            load_lds16(X + (size_t)(m0 + (c >> 2)) * 1024 + k0 + (c & 3) * 8,
                       As + (j * 4 + w) * 512);
            load_lds16(W + (size_t)(n0 + (c >> 2)) * 1024 + k0 + (c & 3) * 8,
                       Bs + (j * 4 + w) * 512);
        }
        __syncthreads();
        short8 af[4], bfr[4];
        #pragma unroll
        for (int mi = 0; mi < 4; ++mi)
            af[mi] = *(const short8*)&As[(wm * 64 + mi * 16 + lq) * 32 + lg * 8];
        #pragma unroll
        for (int ni = 0; ni < 4; ++ni)
            bfr[ni] = *(const short8*)&Bs[(wn * 64 + ni * 16 + lq) * 32 + lg * 8];
        #pragma unroll
        for (int mi = 0; mi < 4; ++mi)
            #pragma unroll
            for (int ni = 0; ni < 4; ++ni)
                acc[mi][ni] = __builtin_amdgcn_mfma_f32_16x16x32_bf16(
                    af[mi], bfr[ni], acc[mi][ni], 0, 0, 0);
    }

    // ---------------- epilogue: bf16 scatter via LDS transpose ----------------
    __syncthreads();  // staging reads complete; reuse smem
    const int part = n0 >> 10;                       // 0=Q 1=K 2=V (uniform)
    const int hh = ((n0 + wn * 64) & 1023) >> 6;     // head (uniform per wave)
    const int mrow0 = m0 + wm * 64;
    const int bh = (mrow0 >> 11) * 16 + hh;
    const int tok0 = mrow0 & 2047;
    // Q pre-scale folds 1/sqrt(64) and log2e for exp2-domain softmax.
    const float scl = (part == 0) ? 0.125f * 1.44269504089f : 1.0f;

    float bias4[4];
    #pragma unroll
    for (int ni = 0; ni < 4; ++ni)
        bias4[ni] = bias[n0 + wn * 64 + ni * 16 + lq];

    uint16_t* T = smem + w * 4608;                   // [64][72] bf16, wave-private
    if (part < 2) {
        #pragma unroll
        for (int mi = 0; mi < 4; ++mi)
            #pragma unroll
            for (int ni = 0; ni < 4; ++ni)
                #pragma unroll
                for (int r = 0; r < 4; ++r)
                    T[(mi * 16 + lg * 4 + r) * 72 + ni * 16 + lq] =
                        f2bf((acc[mi][ni][r] + bias4[ni]) * scl);
    } else {
        #pragma unroll
        for (int mi = 0; mi < 4; ++mi)
            #pragma unroll
            for (int ni = 0; ni < 4; ++ni)
                #pragma unroll
                for (int r = 0; r < 4; ++r)
                    T[(ni * 16 + lq) * 72 + mi * 16 + lg * 4 + r] =
                        f2bf(acc[mi][ni][r] + bias4[ni]);
    }

    const int a0 = l >> 3, b8 = (l & 7) * 8;
    #pragma unroll
    for (int i = 0; i < 8; ++i) {
        int a = i * 8 + a0;
        short8 u = *(short8*)&T[a * 72 + b8];
        uint16_t* p;
        if (part < 2) {
            uint16_t* dst = (part == 0) ? Qb : Kb;
            p = dst + ((size_t)bh * 2048 + tok0 + a) * 64 + b8;
        } else {
            p = Vt + ((size_t)bh * 64 + a) * 2048 + tok0 + b8;
        }
        *(short8*)p = u;
    }
}

// ======================= MFMA flash attention (1-wave blocks) =======================
// 4096 blocks x 64 thr, 3 waves/SIMD (VGPR cap 170; round-7 body = 136, no spill).
// bh = id&31 (id%8 -> XCD affinity), strip = 127-(id>>5) descending work.
// K double-buffered; V(t) + K(t+1) issued before QK(t) (round-7 schedule).
__device__ __forceinline__ void loadKf(const uint16_t* Kb, int kv0, int lq, int lg,
                                       short8 (&d)[8]) {
    #pragma unroll
    for (int n = 0; n < 4; ++n) {
        const uint16_t* kb = Kb + (size_t)(kv0 + n * 16 + lq) * 64 + lg * 8;
        d[2 * n]     = *(const short8*)kb;
        d[2 * n + 1] = *(const short8*)(kb + 32);
    }
}
__device__ __forceinline__ void loadVf(const uint16_t* Vb, int kv0, int lq, int lg,
                                       short8 (&d)[8]) {
    #pragma unroll
    for (int n = 0; n < 4; ++n) {
        const uint16_t* vb = Vb + (size_t)(n * 16 + lq) * 2048 + kv0 + lg * 8;
        d[2 * n]     = *(const short8*)vb;
        d[2 * n + 1] = *(const short8*)(vb + 32);
    }
}

#define DEFER_THR 11.5f   // ~8 nats in log2 units

__global__ __launch_bounds__(64, 3) void attn_mfma(
    const uint16_t* __restrict__ Q, const uint16_t* __restrict__ K,
    const uint16_t* __restrict__ Vt, uint16_t* __restrict__ Y)
{
    const int id = blockIdx.x;
    const int bh = id & 31;               // id%8 -> stable XCD per bh group
    const int strip = 127 - (id >> 5);    // descending work
    const int qt = strip >> 2;            // last kv tile index
    const int q0 = strip * 16;

    const int lane = threadIdx.x;
    const int lq = lane & 15;
    const int lg = lane >> 4;

    __shared__ __align__(16) uint16_t Pl[16][72];

    const uint16_t* Kb = K + (size_t)bh * (2048 * 64);
    const uint16_t* Vb = Vt + (size_t)bh * (64 * 2048);
    const int b = bh >> 4, h = bh & 15;

    const uint16_t* qbase = Q + ((size_t)bh * 2048 + q0 + lq) * 64 + lg * 8;
    short8 qf0 = *(const short8*)qbase;
    short8 qf1 = *(const short8*)(qbase + 32);

    f32x4 y[4] = {};
    float m[4], lsum[4];
    #pragma unroll
    for (int r = 0; r < 4; ++r) { m[r] = -INFINITY; lsum[r] = 0.f; }

    short8 kfA[8], kfB[8], vv[8];
    loadKf(Kb, 0, lq, lg, kfA);

    auto step = [&](short8 (&kf)[8], short8 (&kn)[8], int kt) {
        const int kv0 = kt * 64;
        // issue V(t) and K(t+1) first; QK consumes in-register kf
        loadVf(Vb, kv0, lq, lg, vv);
        if (kt < qt) loadKf(Kb, kv0 + 64, lq, lg, kn);

        f32x4 s[4];
        __builtin_amdgcn_s_setprio(1);
        #pragma unroll
        for (int n = 0; n < 4; ++n) {
            f32x4 z = {};
            z = __builtin_amdgcn_mfma_f32_16x16x32_bf16(qf0, kf[2 * n], z, 0, 0, 0);
            s[n] = __builtin_amdgcn_mfma_f32_16x16x32_bf16(qf1, kf[2 * n + 1], z, 0, 0, 0);
        }
        __builtin_amdgcn_s_setprio(0);

        if (kt == qt) {
            const int rowb = q0 + lg * 4;
            #pragma unroll
            for (int n = 0; n < 4; ++n) {
                int col = kv0 + n * 16 + lq;
                #pragma unroll
                for (int r = 0; r < 4; ++r)
                    if (col > rowb + r) s[n][r] = -INFINITY;
            }
        }
        // ---- online softmax (exp2 domain, defer-max) ----
        float mt[4];
        #pragma unroll
        for (int r = 0; r < 4; ++r)
            mt[r] = fmaxf(fmaxf(s[0][r], s[1][r]), fmaxf(s[2][r], s[3][r]));
        #pragma unroll
        for (int off = 1; off <= 8; off <<= 1)
            #pragma unroll
            for (int r = 0; r < 4; ++r)
                mt[r] = fmaxf(mt[r], __shfl_xor(mt[r], off));

        float g = -INFINITY;
        #pragma unroll
        for (int r = 0; r < 4; ++r) g = fmaxf(g, mt[r] - m[r]);
        const bool skip = __all(g <= DEFER_THR);

        float sc[4];
        if (!skip) {
            #pragma unroll
            for (int r = 0; r < 4; ++r) {
                float mn = fmaxf(m[r], mt[r]);
                sc[r] = exp2f(m[r] - mn);
                m[r] = mn;
            }
        }

        float psum[4] = {0.f, 0.f, 0.f, 0.f};
        #pragma unroll
        for (int n = 0; n < 4; ++n)
            #pragma unroll
            for (int r = 0; r < 4; ++r) {
                float p = exp2f(s[n][r] - m[r]);
                psum[r] += p;
                Pl[lg * 4 + r][n * 16 + lq] = f2bf(p);
            }
        #pragma unroll
        for (int off = 1; off <= 8; off <<= 1)
            #pragma unroll
            for (int r = 0; r < 4; ++r)
                psum[r] += __shfl_xor(psum[r], off);

        if (skip) {
            #pragma unroll
            for (int r = 0; r < 4; ++r) lsum[r] += psum[r];
        } else {
            #pragma unroll
            for (int r = 0; r < 4; ++r) lsum[r] = lsum[r] * sc[r] + psum[r];
            #pragma unroll
            for (int n = 0; n < 4; ++n)
                #pragma unroll
                for (int r = 0; r < 4; ++r)
                    y[n][r] *= sc[r];
        }

        short8 pa0 = *(short8*)&Pl[lq][lg * 8];
        short8 pa1 = *(short8*)&Pl[lq][lg * 8 + 32];
        __builtin_amdgcn_s_setprio(1);
        #pragma unroll
        for (int n = 0; n < 4; ++n) {
            y[n] = __builtin_amdgcn_mfma_f32_16x16x32_bf16(pa0, vv[2 * n], y[n], 0, 0, 0);
            y[n] = __builtin_amdgcn_mfma_f32_16x16x32_bf16(pa1, vv[2 * n + 1], y[n], 0, 0, 0);
        }
        __builtin_amdgcn_s_setprio(0);
    };

    int kt = 0;
    while (true) {
        step(kfA, kfB, kt);
        if (kt == qt) break;
        ++kt;
        step(kfB, kfA, kt);
        if (kt == qt) break;
        ++kt;
    }

    #pragma unroll
    for (int r = 0; r < 4; ++r) {
        float inv = 1.0f / lsum[r];
        int token = b * 2048 + q0 + lg * 4 + r;
        uint16_t* yrow = Y + (size_t)token * 1024 + h * 64;
        #pragma unroll
        for (int n = 0; n < 4; ++n)
            yrow[n * 16 + lq] = f2bf(y[n][r] * inv);
    }
}

// ======================= output projection (MFMA, fp32 out) =======================
// out[4096,1024] = Y(bf16) @ Wo(bf16)^T + bo
__global__ __launch_bounds__(256) void gemm_proj(
    const uint16_t* __restrict__ Yin, const uint16_t* __restrict__ W,
    const float* __restrict__ bias, float* __restrict__ out)
{
    __shared__ __align__(16) uint16_t smem[8192];   // 2 x [128][32]
    uint16_t* As = smem;
    uint16_t* Bs = smem + 4096;

    const int tid = threadIdx.x;
    const int w = tid >> 6, l = tid & 63;
    const int lq = l & 15, lg = l >> 4;
    const int wm = w >> 1, wn = w & 1;
    const int m0 = blockIdx.y * 128;
    const int n0 = blockIdx.x * 128;

    f32x4 acc[4][4] = {};

    for (int k0 = 0; k0 < 1024; k0 += 32) {
        __syncthreads();
        #pragma unroll
        for (int j = 0; j < 2; ++j) {
            const int c = (j * 4 + w) * 64 + l;
            load_lds16(Yin + (size_t)(m0 + (c >> 2)) * 1024 + k0 + (c & 3) * 8,
                       As + (j * 4 + w) * 512);
            load_lds16(W + (size_t)(n0 + (c >> 2)) * 1024 + k0 + (c & 3) * 8,
                       Bs + (j * 4 + w) * 512);
        }
        __syncthreads();
        short8 af[4], bfr[4];
        #pragma unroll
        for (int mi = 0; mi < 4; ++mi)
            af[mi] = *(const short8*)&As[(wm * 64 + mi * 16 + lq) * 32 + lg * 8];
        #pragma unroll
        for (int ni = 0; ni < 4; ++ni)
            bfr[ni] = *(const short8*)&Bs[(wn * 64 + ni * 16 + lq) * 32 + lg * 8];
        #pragma unroll
        for (int mi = 0; mi < 4; ++mi)
            #pragma unroll
            for (int ni = 0; ni < 4; ++ni)
                acc[mi][ni] = __builtin_amdgcn_mfma_f32_16x16x32_bf16(
                    af[mi], bfr[ni], acc[mi][ni], 0, 0, 0);
    }

    // epilogue: direct fp32 stores from C-fragment layout
    const int mrow0 = m0 + wm * 64;
    const int ncol0 = n0 + wn * 64;
    float bias4[4];
    #pragma unroll
    for (int ni = 0; ni < 4; ++ni)
        bias4[ni] = bias[ncol0 + ni * 16 + lq];

    #pragma unroll
    for (int mi = 0; mi < 4; ++mi)
        #pragma unroll
        for (int r = 0; r < 4; ++r) {
            const size_t rowoff = (size_t)(mrow0 + mi * 16 + lg * 4 + r) * 1024;
            #pragma unroll
            for (int ni = 0; ni < 4; ++ni)
                out[rowoff + ncol0 + ni * 16 + lq] = acc[mi][ni][r] + bias4[ni];
        }
}

// ======================= launcher =======================

extern "C" void kernel_launch(void* const* d_in, const int* in_sizes, int n_in,
                              void* d_out, int out_size, void* d_ws, size_t ws_size,
                              hipStream_t stream) {
    const float* x    = (const float*)d_in[0];
    // d_in[1] (causal mask) applied structurally.
    const float* Wqkv = (const float*)d_in[2];
    const float* bqkv = (const float*)d_in[3];
    const float* Wo   = (const float*)d_in[4];
    const float* bo   = (const float*)d_in[5];

    const size_t QK = (size_t)BB * HH * NN * SS;  // 4,194,304

    uint16_t* Xb  = (uint16_t*)d_ws;
    uint16_t* Wqb = Xb + XE;
    uint16_t* Wob = Wqb + WQE;
    uint16_t* Qb  = Wob + WOE;
    uint16_t* Kb  = Qb + QK;
    uint16_t* Vt  = Kb + QK;
    uint16_t* Yb  = Vt + QK;

    cvt_all<<<(XE + WQE + WOE) / 8 / 256, 256, 0, stream>>>(x, Wqkv, Wo, Xb);
    gemm_qkv<<<dim3(24, 32), 256, 0, stream>>>(Xb, Wqb, bqkv, Qb, Kb, Vt);
    attn_mfma<<<4096, 64, 0, stream>>>(Qb, Kb, Vt, Yb);
    gemm_proj<<<dim3(8, 32), 256, 0, stream>>>(Yb, Wob, bo, (float*)d_out);
}

// Round 10
// 205.297 us; speedup vs baseline: 1.2065x; 1.1280x over previous
//
#include <hip/hip_runtime.h>
#include <hip/hip_bf16.h>
#include <stdint.h>

// Problem constants: B=2, N=2048, D=1024, H=16, head dim s=64.
// Global I/O fp32; internal X/W/Q/K/V/Y intermediates bf16 in d_ws.
// Q is pre-scaled by 0.125*log2e so attention softmax runs in exp2 domain.
#define BB 2
#define NN 2048
#define DD 1024
#define HH 16
#define SS 64

typedef short short8 __attribute__((ext_vector_type(8)));
typedef float f32x4 __attribute__((ext_vector_type(4)));

__device__ __forceinline__ float bf2f(uint16_t u) {
    return __uint_as_float(((uint32_t)u) << 16);
}
__device__ __forceinline__ uint16_t f2bf(float f) {
    uint32_t u = __float_as_uint(f);
    return (uint16_t)((u + 0x7FFFu + ((u >> 16) & 1u)) >> 16);  // RNE
}
__device__ __forceinline__ short8 cvt8(float4 a, float4 b) {
    short8 s;
    s[0] = (short)f2bf(a.x); s[1] = (short)f2bf(a.y);
    s[2] = (short)f2bf(a.z); s[3] = (short)f2bf(a.w);
    s[4] = (short)f2bf(b.x); s[5] = (short)f2bf(b.y);
    s[6] = (short)f2bf(b.z); s[7] = (short)f2bf(b.w);
    return s;
}

__device__ __forceinline__ void load_lds16(const uint16_t* g, uint16_t* l) {
    __builtin_amdgcn_global_load_lds(
        (const __attribute__((address_space(1))) void*)g,
        (__attribute__((address_space(3))) void*)l, 16, 0, 0);
}

#define XE  (4096 * 1024)
#define WQE (3072 * 1024)
#define WOE (1024 * 1024)

// ======================= fused fp32 -> bf16 bulk convert =======================
__global__ __launch_bounds__(256) void cvt_all(
    const float* __restrict__ x, const float* __restrict__ wq,
    const float* __restrict__ wo, uint16_t* __restrict__ dst)
{
    int i = (blockIdx.x * 256 + threadIdx.x) * 8;
    const float* src;
    int off;
    if (i < XE)            { src = x;  off = i; }
    else if (i < XE + WQE) { src = wq; off = i - XE; }
    else                   { src = wo; off = i - XE - WQE; }
    float4 a = *(const float4*)(src + off);
    float4 b = *(const float4*)(src + off + 4);
    *(short8*)(dst + i) = cvt8(a, b);
}

// ======================= QKV projection (MFMA, bf16 in) =======================
// C[4096,3072] = X[4096,1024] @ Wqkv[3072,1024]^T + bqkv
// -> Q bf16 (x0.125*log2e) [bh][2048][64], K bf16 [bh][2048][64], V^T [bh][64][2048]
__global__ __launch_bounds__(256) void gemm_qkv(
    const uint16_t* __restrict__ X, const uint16_t* __restrict__ W,
    const float* __restrict__ bias,
    uint16_t* __restrict__ Qb, uint16_t* __restrict__ Kb, uint16_t* __restrict__ Vt)
{
    __shared__ __align__(16) uint16_t smem[18432];   // 36,864 B
    uint16_t* As = smem;          // [128][32] linear (gload_lds requires)
    uint16_t* Bs = smem + 4096;   // [128][32]

    const int tid = threadIdx.x;
    const int w = tid >> 6, l = tid & 63;
    const int lq = l & 15, lg = l >> 4;
    const int wm = w >> 1, wn = w & 1;
    const int m0 = blockIdx.y * 128;
    const int n0 = blockIdx.x * 128;

    f32x4 acc[4][4] = {};

    for (int k0 = 0; k0 < 1024; k0 += 32) {
        __syncthreads();
        #pragma unroll
        for (int j = 0; j < 2; ++j) {
            const int c = (j * 4 + w) * 64 + l;   // lane's global row/col chunk
            load_lds16(X + (size_t)(m0 + (c >> 2)) * 1024 + k0 + (c & 3) * 8,
                       As + (j * 4 + w) * 512);
            load_lds16(W + (size_t)(n0 + (c >> 2)) * 1024 + k0 + (c & 3) * 8,
                       Bs + (j * 4 + w) * 512);
        }
        __syncthreads();
        short8 af[4], bfr[4];
        #pragma unroll
        for (int mi = 0; mi < 4; ++mi)
            af[mi] = *(const short8*)&As[(wm * 64 + mi * 16 + lq) * 32 + lg * 8];
        #pragma unroll
        for (int ni = 0; ni < 4; ++ni)
            bfr[ni] = *(const short8*)&Bs[(wn * 64 + ni * 16 + lq) * 32 + lg * 8];
        #pragma unroll
        for (int mi = 0; mi < 4; ++mi)
            #pragma unroll
            for (int ni = 0; ni < 4; ++ni)
                acc[mi][ni] = __builtin_amdgcn_mfma_f32_16x16x32_bf16(
                    af[mi], bfr[ni], acc[mi][ni], 0, 0, 0);
    }

    // ---------------- epilogue: bf16 scatter via LDS transpose ----------------
    __syncthreads();  // staging reads complete; reuse smem
    const int part = n0 >> 10;                       // 0=Q 1=K 2=V (uniform)
    const int hh = ((n0 + wn * 64) & 1023) >> 6;     // head (uniform per wave)
    const int mrow0 = m0 + wm * 64;
    const int bh = (mrow0 >> 11) * 16 + hh;
    const int tok0 = mrow0 & 2047;
    // Q pre-scale folds 1/sqrt(64) and log2e for exp2-domain softmax.
    const float scl = (part == 0) ? 0.125f * 1.44269504089f : 1.0f;

    float bias4[4];
    #pragma unroll
    for (int ni = 0; ni < 4; ++ni)
        bias4[ni] = bias[n0 + wn * 64 + ni * 16 + lq];

    uint16_t* T = smem + w * 4608;                   // [64][72] bf16, wave-private
    if (part < 2) {
        #pragma unroll
        for (int mi = 0; mi < 4; ++mi)
            #pragma unroll
            for (int ni = 0; ni < 4; ++ni)
                #pragma unroll
                for (int r = 0; r < 4; ++r)
                    T[(mi * 16 + lg * 4 + r) * 72 + ni * 16 + lq] =
                        f2bf((acc[mi][ni][r] + bias4[ni]) * scl);
    } else {
        #pragma unroll
        for (int mi = 0; mi < 4; ++mi)
            #pragma unroll
            for (int ni = 0; ni < 4; ++ni)
                #pragma unroll
                for (int r = 0; r < 4; ++r)
                    T[(ni * 16 + lq) * 72 + mi * 16 + lg * 4 + r] =
                        f2bf(acc[mi][ni][r] + bias4[ni]);
    }

    const int a0 = l >> 3, b8 = (l & 7) * 8;
    #pragma unroll
    for (int i = 0; i < 8; ++i) {
        int a = i * 8 + a0;
        short8 u = *(short8*)&T[a * 72 + b8];
        uint16_t* p;
        if (part < 2) {
            uint16_t* dst = (part == 0) ? Qb : Kb;
            p = dst + ((size_t)bh * 2048 + tok0 + a) * 64 + b8;
        } else {
            p = Vt + ((size_t)bh * 64 + a) * 2048 + tok0 + b8;
        }
        *(short8*)p = u;
    }
}

// ======================= MFMA flash attention (1-wave blocks) =======================
// 4096 blocks x 64 thr. NO second launch_bounds arg: the (64,N) caps forced
// catastrophic scratch spills (r8: 45MB, r9: 98MB writes). Natural allocation
// (~136-170 VGPR) gives 3 waves/SIMD from the 512-reg/SIMD pool with 0 spill.
// bh = id&31 (id%8 -> XCD affinity), strip = 127-(id>>5) descending work.
__device__ __forceinline__ void loadKf(const uint16_t* Kb, int kv0, int lq, int lg,
                                       short8 (&d)[8]) {
    #pragma unroll
    for (int n = 0; n < 4; ++n) {
        const uint16_t* kb = Kb + (size_t)(kv0 + n * 16 + lq) * 64 + lg * 8;
        d[2 * n]     = *(const short8*)kb;
        d[2 * n + 1] = *(const short8*)(kb + 32);
    }
}
__device__ __forceinline__ void loadVf(const uint16_t* Vb, int kv0, int lq, int lg,
                                       short8 (&d)[8]) {
    #pragma unroll
    for (int n = 0; n < 4; ++n) {
        const uint16_t* vb = Vb + (size_t)(n * 16 + lq) * 2048 + kv0 + lg * 8;
        d[2 * n]     = *(const short8*)vb;
        d[2 * n + 1] = *(const short8*)(vb + 32);
    }
}

#define DEFER_THR 11.5f   // ~8 nats in log2 units

__global__ __launch_bounds__(64) void attn_mfma(
    const uint16_t* __restrict__ Q, const uint16_t* __restrict__ K,
    const uint16_t* __restrict__ Vt, uint16_t* __restrict__ Y)
{
    const int id = blockIdx.x;
    const int bh = id & 31;               // id%8 -> stable XCD per bh group
    const int strip = 127 - (id >> 5);    // descending work
    const int qt = strip >> 2;            // last kv tile index
    const int q0 = strip * 16;

    const int lane = threadIdx.x;
    const int lq = lane & 15;
    const int lg = lane >> 4;

    __shared__ __align__(16) uint16_t Pl[16][72];

    const uint16_t* Kb = K + (size_t)bh * (2048 * 64);
    const uint16_t* Vb = Vt + (size_t)bh * (64 * 2048);
    const int b = bh >> 4, h = bh & 15;

    const uint16_t* qbase = Q + ((size_t)bh * 2048 + q0 + lq) * 64 + lg * 8;
    short8 qf0 = *(const short8*)qbase;
    short8 qf1 = *(const short8*)(qbase + 32);

    f32x4 y[4] = {};
    float m[4], lsum[4];
    #pragma unroll
    for (int r = 0; r < 4; ++r) { m[r] = -INFINITY; lsum[r] = 0.f; }

    short8 kfA[8], kfB[8], vv[8];
    loadKf(Kb, 0, lq, lg, kfA);

    auto step = [&](short8 (&kf)[8], short8 (&kn)[8], int kt) {
        const int kv0 = kt * 64;
        // issue V(t) and K(t+1) first; QK consumes in-register kf
        loadVf(Vb, kv0, lq, lg, vv);
        if (kt < qt) loadKf(Kb, kv0 + 64, lq, lg, kn);

        f32x4 s[4];
        __builtin_amdgcn_s_setprio(1);
        #pragma unroll
        for (int n = 0; n < 4; ++n) {
            f32x4 z = {};
            z = __builtin_amdgcn_mfma_f32_16x16x32_bf16(qf0, kf[2 * n], z, 0, 0, 0);
            s[n] = __builtin_amdgcn_mfma_f32_16x16x32_bf16(qf1, kf[2 * n + 1], z, 0, 0, 0);
        }
        __builtin_amdgcn_s_setprio(0);

        if (kt == qt) {
            const int rowb = q0 + lg * 4;
            #pragma unroll
            for (int n = 0; n < 4; ++n) {
                int col = kv0 + n * 16 + lq;
                #pragma unroll
                for (int r = 0; r < 4; ++r)
                    if (col > rowb + r) s[n][r] = -INFINITY;
            }
        }
        // ---- online softmax (exp2 domain, defer-max) ----
        float mt[4];
        #pragma unroll
        for (int r = 0; r < 4; ++r)
            mt[r] = fmaxf(fmaxf(s[0][r], s[1][r]), fmaxf(s[2][r], s[3][r]));
        #pragma unroll
        for (int off = 1; off <= 8; off <<= 1)
            #pragma unroll
            for (int r = 0; r < 4; ++r)
                mt[r] = fmaxf(mt[r], __shfl_xor(mt[r], off));

        float g = -INFINITY;
        #pragma unroll
        for (int r = 0; r < 4; ++r) g = fmaxf(g, mt[r] - m[r]);
        const bool skip = __all(g <= DEFER_THR);

        float sc[4];
        if (!skip) {
            #pragma unroll
            for (int r = 0; r < 4; ++r) {
                float mn = fmaxf(m[r], mt[r]);
                sc[r] = exp2f(m[r] - mn);
                m[r] = mn;
            }
        }

        float psum[4] = {0.f, 0.f, 0.f, 0.f};
        #pragma unroll
        for (int n = 0; n < 4; ++n)
            #pragma unroll
            for (int r = 0; r < 4; ++r) {
                float p = exp2f(s[n][r] - m[r]);
                psum[r] += p;
                Pl[lg * 4 + r][n * 16 + lq] = f2bf(p);
            }
        #pragma unroll
        for (int off = 1; off <= 8; off <<= 1)
            #pragma unroll
            for (int r = 0; r < 4; ++r)
                psum[r] += __shfl_xor(psum[r], off);

        if (skip) {
            #pragma unroll
            for (int r = 0; r < 4; ++r) lsum[r] += psum[r];
        } else {
            #pragma unroll
            for (int r = 0; r < 4; ++r) lsum[r] = lsum[r] * sc[r] + psum[r];
            #pragma unroll
            for (int n = 0; n < 4; ++n)
                #pragma unroll
                for (int r = 0; r < 4; ++r)
                    y[n][r] *= sc[r];
        }

        short8 pa0 = *(short8*)&Pl[lq][lg * 8];
        short8 pa1 = *(short8*)&Pl[lq][lg * 8 + 32];
        __builtin_amdgcn_s_setprio(1);
        #pragma unroll
        for (int n = 0; n < 4; ++n) {
            y[n] = __builtin_amdgcn_mfma_f32_16x16x32_bf16(pa0, vv[2 * n], y[n], 0, 0, 0);
            y[n] = __builtin_amdgcn_mfma_f32_16x16x32_bf16(pa1, vv[2 * n + 1], y[n], 0, 0, 0);
        }
        __builtin_amdgcn_s_setprio(0);
    };

    int kt = 0;
    while (true) {
        step(kfA, kfB, kt);
        if (kt == qt) break;
        ++kt;
        step(kfB, kfA, kt);
        if (kt == qt) break;
        ++kt;
    }

    #pragma unroll
    for (int r = 0; r < 4; ++r) {
        float inv = 1.0f / lsum[r];
        int token = b * 2048 + q0 + lg * 4 + r;
        uint16_t* yrow = Y + (size_t)token * 1024 + h * 64;
        #pragma unroll
        for (int n = 0; n < 4; ++n)
            yrow[n * 16 + lq] = f2bf(y[n][r] * inv);
    }
}

// ======================= output projection (MFMA, fp32 out) =======================
// out[4096,1024] = Y(bf16) @ Wo(bf16)^T + bo
__global__ __launch_bounds__(256) void gemm_proj(
    const uint16_t* __restrict__ Yin, const uint16_t* __restrict__ W,
    const float* __restrict__ bias, float* __restrict__ out)
{
    __shared__ __align__(16) uint16_t smem[8192];   // 2 x [128][32]
    uint16_t* As = smem;
    uint16_t* Bs = smem + 4096;

    const int tid = threadIdx.x;
    const int w = tid >> 6, l = tid & 63;
    const int lq = l & 15, lg = l >> 4;
    const int wm = w >> 1, wn = w & 1;
    const int m0 = blockIdx.y * 128;
    const int n0 = blockIdx.x * 128;

    f32x4 acc[4][4] = {};

    for (int k0 = 0; k0 < 1024; k0 += 32) {
        __syncthreads();
        #pragma unroll
        for (int j = 0; j < 2; ++j) {
            const int c = (j * 4 + w) * 64 + l;
            load_lds16(Yin + (size_t)(m0 + (c >> 2)) * 1024 + k0 + (c & 3) * 8,
                       As + (j * 4 + w) * 512);
            load_lds16(W + (size_t)(n0 + (c >> 2)) * 1024 + k0 + (c & 3) * 8,
                       Bs + (j * 4 + w) * 512);
        }
        __syncthreads();
        short8 af[4], bfr[4];
        #pragma unroll
        for (int mi = 0; mi < 4; ++mi)
            af[mi] = *(const short8*)&As[(wm * 64 + mi * 16 + lq) * 32 + lg * 8];
        #pragma unroll
        for (int ni = 0; ni < 4; ++ni)
            bfr[ni] = *(const short8*)&Bs[(wn * 64 + ni * 16 + lq) * 32 + lg * 8];
        #pragma unroll
        for (int mi = 0; mi < 4; ++mi)
            #pragma unroll
            for (int ni = 0; ni < 4; ++ni)
                acc[mi][ni] = __builtin_amdgcn_mfma_f32_16x16x32_bf16(
                    af[mi], bfr[ni], acc[mi][ni], 0, 0, 0);
    }

    // epilogue: direct fp32 stores from C-fragment layout
    const int mrow0 = m0 + wm * 64;
    const int ncol0 = n0 + wn * 64;
    float bias4[4];
    #pragma unroll
    for (int ni = 0; ni < 4; ++ni)
        bias4[ni] = bias[ncol0 + ni * 16 + lq];

    #pragma unroll
    for (int mi = 0; mi < 4; ++mi)
        #pragma unroll
        for (int r = 0; r < 4; ++r) {
            const size_t rowoff = (size_t)(mrow0 + mi * 16 + lg * 4 + r) * 1024;
            #pragma unroll
            for (int ni = 0; ni < 4; ++ni)
                out[rowoff + ncol0 + ni * 16 + lq] = acc[mi][ni][r] + bias4[ni];
        }
}

// ======================= launcher =======================

extern "C" void kernel_launch(void* const* d_in, const int* in_sizes, int n_in,
                              void* d_out, int out_size, void* d_ws, size_t ws_size,
                              hipStream_t stream) {
    const float* x    = (const float*)d_in[0];
    // d_in[1] (causal mask) applied structurally.
    const float* Wqkv = (const float*)d_in[2];
    const float* bqkv = (const float*)d_in[3];
    const float* Wo   = (const float*)d_in[4];
    const float* bo   = (const float*)d_in[5];

    const size_t QK = (size_t)BB * HH * NN * SS;  // 4,194,304

    uint16_t* Xb  = (uint16_t*)d_ws;
    uint16_t* Wqb = Xb + XE;
    uint16_t* Wob = Wqb + WQE;
    uint16_t* Qb  = Wob + WOE;
    uint16_t* Kb  = Qb + QK;
    uint16_t* Vt  = Kb + QK;
    uint16_t* Yb  = Vt + QK;

    cvt_all<<<(XE + WQE + WOE) / 8 / 256, 256, 0, stream>>>(x, Wqkv, Wo, Xb);
    gemm_qkv<<<dim3(24, 32), 256, 0, stream>>>(Xb, Wqb, bqkv, Qb, Kb, Vt);
    attn_mfma<<<4096, 64, 0, stream>>>(Qb, Kb, Vt, Yb);
    gemm_proj<<<dim3(8, 32), 256, 0, stream>>>(Yb, Wob, bo, (float*)d_out);
}

// Round 11
// 203.960 us; speedup vs baseline: 1.2144x; 1.0066x over previous
//
#include <hip/hip_runtime.h>
#include <hip/hip_bf16.h>
#include <stdint.h>

// Problem constants: B=2, N=2048, D=1024, H=16, head dim s=64.
// Global I/O fp32; internal X/W/Q/K/V/Y intermediates bf16 in d_ws.
// Q is pre-scaled by 0.125*log2e so attention softmax runs in exp2 domain.
#define BB 2
#define NN 2048
#define DD 1024
#define HH 16
#define SS 64

typedef short short8 __attribute__((ext_vector_type(8)));
typedef float f32x4 __attribute__((ext_vector_type(4)));

__device__ __forceinline__ float bf2f(uint16_t u) {
    return __uint_as_float(((uint32_t)u) << 16);
}
__device__ __forceinline__ uint16_t f2bf(float f) {
    uint32_t u = __float_as_uint(f);
    return (uint16_t)((u + 0x7FFFu + ((u >> 16) & 1u)) >> 16);  // RNE
}
__device__ __forceinline__ short8 cvt8(float4 a, float4 b) {
    short8 s;
    s[0] = (short)f2bf(a.x); s[1] = (short)f2bf(a.y);
    s[2] = (short)f2bf(a.z); s[3] = (short)f2bf(a.w);
    s[4] = (short)f2bf(b.x); s[5] = (short)f2bf(b.y);
    s[6] = (short)f2bf(b.z); s[7] = (short)f2bf(b.w);
    return s;
}

__device__ __forceinline__ void load_lds16(const uint16_t* g, uint16_t* l) {
    __builtin_amdgcn_global_load_lds(
        (const __attribute__((address_space(1))) void*)g,
        (__attribute__((address_space(3))) void*)l, 16, 0, 0);
}

#define XE  (4096 * 1024)
#define WQE (3072 * 1024)
#define WOE (1024 * 1024)

// ======================= fused fp32 -> bf16 bulk convert =======================
__global__ __launch_bounds__(256) void cvt_all(
    const float* __restrict__ x, const float* __restrict__ wq,
    const float* __restrict__ wo, uint16_t* __restrict__ dst)
{
    int i = (blockIdx.x * 256 + threadIdx.x) * 8;
    const float* src;
    int off;
    if (i < XE)            { src = x;  off = i; }
    else if (i < XE + WQE) { src = wq; off = i - XE; }
    else                   { src = wo; off = i - XE - WQE; }
    float4 a = *(const float4*)(src + off);
    float4 b = *(const float4*)(src + off + 4);
    *(short8*)(dst + i) = cvt8(a, b);
}

// ======================= QKV projection (MFMA, bf16 in) =======================
// C[4096,3072] = X[4096,1024] @ Wqkv[3072,1024]^T + bqkv
// -> Q bf16 (x0.125*log2e) [bh][2048][64], K bf16 [bh][2048][64], V^T [bh][64][2048]
__global__ __launch_bounds__(256) void gemm_qkv(
    const uint16_t* __restrict__ X, const uint16_t* __restrict__ W,
    const float* __restrict__ bias,
    uint16_t* __restrict__ Qb, uint16_t* __restrict__ Kb, uint16_t* __restrict__ Vt)
{
    __shared__ __align__(16) uint16_t smem[18432];   // 36,864 B
    uint16_t* As = smem;          // [128][32] linear (gload_lds requires)
    uint16_t* Bs = smem + 4096;   // [128][32]

    const int tid = threadIdx.x;
    const int w = tid >> 6, l = tid & 63;
    const int lq = l & 15, lg = l >> 4;
    const int wm = w >> 1, wn = w & 1;
    const int m0 = blockIdx.y * 128;
    const int n0 = blockIdx.x * 128;

    f32x4 acc[4][4] = {};

    for (int k0 = 0; k0 < 1024; k0 += 32) {
        __syncthreads();
        #pragma unroll
        for (int j = 0; j < 2; ++j) {
            const int c = (j * 4 + w) * 64 + l;   // lane's global row/col chunk
            load_lds16(X + (size_t)(m0 + (c >> 2)) * 1024 + k0 + (c & 3) * 8,
                       As + (j * 4 + w) * 512);
            load_lds16(W + (size_t)(n0 + (c >> 2)) * 1024 + k0 + (c & 3) * 8,
                       Bs + (j * 4 + w) * 512);
        }
        __syncthreads();
        short8 af[4], bfr[4];
        #pragma unroll
        for (int mi = 0; mi < 4; ++mi)
            af[mi] = *(const short8*)&As[(wm * 64 + mi * 16 + lq) * 32 + lg * 8];
        #pragma unroll
        for (int ni = 0; ni < 4; ++ni)
            bfr[ni] = *(const short8*)&Bs[(wn * 64 + ni * 16 + lq) * 32 + lg * 8];
        #pragma unroll
        for (int mi = 0; mi < 4; ++mi)
            #pragma unroll
            for (int ni = 0; ni < 4; ++ni)
                acc[mi][ni] = __builtin_amdgcn_mfma_f32_16x16x32_bf16(
                    af[mi], bfr[ni], acc[mi][ni], 0, 0, 0);
    }

    // ---------------- epilogue: bf16 scatter via LDS transpose ----------------
    __syncthreads();  // staging reads complete; reuse smem
    const int part = n0 >> 10;                       // 0=Q 1=K 2=V (uniform)
    const int hh = ((n0 + wn * 64) & 1023) >> 6;     // head (uniform per wave)
    const int mrow0 = m0 + wm * 64;
    const int bh = (mrow0 >> 11) * 16 + hh;
    const int tok0 = mrow0 & 2047;
    // Q pre-scale folds 1/sqrt(64) and log2e for exp2-domain softmax.
    const float scl = (part == 0) ? 0.125f * 1.44269504089f : 1.0f;

    float bias4[4];
    #pragma unroll
    for (int ni = 0; ni < 4; ++ni)
        bias4[ni] = bias[n0 + wn * 64 + ni * 16 + lq];

    uint16_t* T = smem + w * 4608;                   // [64][72] bf16, wave-private
    if (part < 2) {
        #pragma unroll
        for (int mi = 0; mi < 4; ++mi)
            #pragma unroll
            for (int ni = 0; ni < 4; ++ni)
                #pragma unroll
                for (int r = 0; r < 4; ++r)
                    T[(mi * 16 + lg * 4 + r) * 72 + ni * 16 + lq] =
                        f2bf((acc[mi][ni][r] + bias4[ni]) * scl);
    } else {
        #pragma unroll
        for (int mi = 0; mi < 4; ++mi)
            #pragma unroll
            for (int ni = 0; ni < 4; ++ni)
                #pragma unroll
                for (int r = 0; r < 4; ++r)
                    T[(ni * 16 + lq) * 72 + mi * 16 + lg * 4 + r] =
                        f2bf(acc[mi][ni][r] + bias4[ni]);
    }

    const int a0 = l >> 3, b8 = (l & 7) * 8;
    #pragma unroll
    for (int i = 0; i < 8; ++i) {
        int a = i * 8 + a0;
        short8 u = *(short8*)&T[a * 72 + b8];
        uint16_t* p;
        if (part < 2) {
            uint16_t* dst = (part == 0) ? Qb : Kb;
            p = dst + ((size_t)bh * 2048 + tok0 + a) * 64 + b8;
        } else {
            p = Vt + ((size_t)bh * 64 + a) * 2048 + tok0 + b8;
        }
        *(short8*)p = u;
    }
}

// ======================= MFMA flash attention (1-wave blocks) =======================
// 4096 blocks x 64 thr, no launch_bounds cap (r8/r9: caps caused huge spills).
// Softmax fast path: per-lane defer check (3 fmax + __all == exact reduced
// condition) and PER-LANE partial lsum (cross-lane reduce ONCE in epilogue) --
// removes both 4-round ds_bpermute chains from the steady-state kv-step.
__device__ __forceinline__ void loadKf(const uint16_t* Kb, int kv0, int lq, int lg,
                                       short8 (&d)[8]) {
    #pragma unroll
    for (int n = 0; n < 4; ++n) {
        const uint16_t* kb = Kb + (size_t)(kv0 + n * 16 + lq) * 64 + lg * 8;
        d[2 * n]     = *(const short8*)kb;
        d[2 * n + 1] = *(const short8*)(kb + 32);
    }
}
__device__ __forceinline__ void loadVf(const uint16_t* Vb, int kv0, int lq, int lg,
                                       short8 (&d)[8]) {
    #pragma unroll
    for (int n = 0; n < 4; ++n) {
        const uint16_t* vb = Vb + (size_t)(n * 16 + lq) * 2048 + kv0 + lg * 8;
        d[2 * n]     = *(const short8*)vb;
        d[2 * n + 1] = *(const short8*)(vb + 32);
    }
}

#define DEFER_THR 11.5f   // ~8 nats in log2 units

__global__ __launch_bounds__(64) void attn_mfma(
    const uint16_t* __restrict__ Q, const uint16_t* __restrict__ K,
    const uint16_t* __restrict__ Vt, uint16_t* __restrict__ Y)
{
    const int id = blockIdx.x;
    const int bh = id & 31;               // id%8 -> stable XCD per bh group
    const int strip = 127 - (id >> 5);    // descending work
    const int qt = strip >> 2;            // last kv tile index
    const int q0 = strip * 16;

    const int lane = threadIdx.x;
    const int lq = lane & 15;
    const int lg = lane >> 4;

    __shared__ __align__(16) uint16_t Pl[16][72];

    const uint16_t* Kb = K + (size_t)bh * (2048 * 64);
    const uint16_t* Vb = Vt + (size_t)bh * (64 * 2048);
    const int b = bh >> 4, h = bh & 15;

    const uint16_t* qbase = Q + ((size_t)bh * 2048 + q0 + lq) * 64 + lg * 8;
    short8 qf0 = *(const short8*)qbase;
    short8 qf1 = *(const short8*)(qbase + 32);

    f32x4 y[4] = {};
    float m[4], lsum[4];   // lsum = PER-LANE partial (this lane's key columns)
    #pragma unroll
    for (int r = 0; r < 4; ++r) { m[r] = -INFINITY; lsum[r] = 0.f; }

    short8 kfA[8], kfB[8], vv[8];
    loadKf(Kb, 0, lq, lg, kfA);

    auto step = [&](short8 (&kf)[8], short8 (&kn)[8], int kt) {
        const int kv0 = kt * 64;
        // issue V(t) and K(t+1) first; QK consumes in-register kf
        loadVf(Vb, kv0, lq, lg, vv);
        if (kt < qt) loadKf(Kb, kv0 + 64, lq, lg, kn);

        f32x4 s[4];
        __builtin_amdgcn_s_setprio(1);
        #pragma unroll
        for (int n = 0; n < 4; ++n) {
            f32x4 z = {};
            z = __builtin_amdgcn_mfma_f32_16x16x32_bf16(qf0, kf[2 * n], z, 0, 0, 0);
            s[n] = __builtin_amdgcn_mfma_f32_16x16x32_bf16(qf1, kf[2 * n + 1], z, 0, 0, 0);
        }
        __builtin_amdgcn_s_setprio(0);

        if (kt == qt) {
            const int rowb = q0 + lg * 4;
            #pragma unroll
            for (int n = 0; n < 4; ++n) {
                int col = kv0 + n * 16 + lq;
                #pragma unroll
                for (int r = 0; r < 4; ++r)
                    if (col > rowb + r) s[n][r] = -INFINITY;
            }
        }
        // ---- defer check: per-lane local max, one ballot (== reduced cond) ----
        float mt[4];
        #pragma unroll
        for (int r = 0; r < 4; ++r)
            mt[r] = fmaxf(fmaxf(s[0][r], s[1][r]), fmaxf(s[2][r], s[3][r]));
        float g = -INFINITY;
        #pragma unroll
        for (int r = 0; r < 4; ++r) g = fmaxf(g, mt[r] - m[r]);
        const bool skip = __all(g <= DEFER_THR);

        if (!skip) {   // rare: full cross-lane max reduce + rescale
            #pragma unroll
            for (int off = 1; off <= 8; off <<= 1)
                #pragma unroll
                for (int r = 0; r < 4; ++r)
                    mt[r] = fmaxf(mt[r], __shfl_xor(mt[r], off));
            float sc[4];
            #pragma unroll
            for (int r = 0; r < 4; ++r) {
                float mn = fmaxf(m[r], mt[r]);
                sc[r] = exp2f(m[r] - mn);
                m[r] = mn;
            }
            #pragma unroll
            for (int r = 0; r < 4; ++r) lsum[r] *= sc[r];
            #pragma unroll
            for (int n = 0; n < 4; ++n)
                #pragma unroll
                for (int r = 0; r < 4; ++r)
                    y[n][r] *= sc[r];
        }

        // ---- exp2 + per-lane psum; P writes split around pa reads ----
        float ps[4] = {0.f, 0.f, 0.f, 0.f};
        #pragma unroll
        for (int n = 0; n < 2; ++n)
            #pragma unroll
            for (int r = 0; r < 4; ++r) {
                float p = exp2f(s[n][r] - m[r]);
                ps[r] += p;
                Pl[lg * 4 + r][n * 16 + lq] = f2bf(p);
            }
        short8 pa0 = *(short8*)&Pl[lq][lg * 8];          // cols 0..31 (n=0,1)
        #pragma unroll
        for (int n = 2; n < 4; ++n)
            #pragma unroll
            for (int r = 0; r < 4; ++r) {
                float p = exp2f(s[n][r] - m[r]);
                ps[r] += p;
                Pl[lg * 4 + r][n * 16 + lq] = f2bf(p);
            }
        short8 pa1 = *(short8*)&Pl[lq][lg * 8 + 32];     // cols 32..63 (n=2,3)

        #pragma unroll
        for (int r = 0; r < 4; ++r) lsum[r] += ps[r];

        __builtin_amdgcn_s_setprio(1);
        #pragma unroll
        for (int n = 0; n < 4; ++n) {
            y[n] = __builtin_amdgcn_mfma_f32_16x16x32_bf16(pa0, vv[2 * n], y[n], 0, 0, 0);
            y[n] = __builtin_amdgcn_mfma_f32_16x16x32_bf16(pa1, vv[2 * n + 1], y[n], 0, 0, 0);
        }
        __builtin_amdgcn_s_setprio(0);
    };

    int kt = 0;
    while (true) {
        step(kfA, kfB, kt);
        if (kt == qt) break;
        ++kt;
        step(kfB, kfA, kt);
        if (kt == qt) break;
        ++kt;
    }

    // ---- final cross-lane lsum reduce (once per block) ----
    #pragma unroll
    for (int off = 1; off <= 8; off <<= 1)
        #pragma unroll
        for (int r = 0; r < 4; ++r)
            lsum[r] += __shfl_xor(lsum[r], off);

    #pragma unroll
    for (int r = 0; r < 4; ++r) {
        float inv = 1.0f / lsum[r];
        int token = b * 2048 + q0 + lg * 4 + r;
        uint16_t* yrow = Y + (size_t)token * 1024 + h * 64;
        #pragma unroll
        for (int n = 0; n < 4; ++n)
            yrow[n * 16 + lq] = f2bf(y[n][r] * inv);
    }
}

// ======================= output projection (MFMA, fp32 out) =======================
// out[4096,1024] = Y(bf16) @ Wo(bf16)^T + bo
__global__ __launch_bounds__(256) void gemm_proj(
    const uint16_t* __restrict__ Yin, const uint16_t* __restrict__ W,
    const float* __restrict__ bias, float* __restrict__ out)
{
    __shared__ __align__(16) uint16_t smem[8192];   // 2 x [128][32]
    uint16_t* As = smem;
    uint16_t* Bs = smem + 4096;

    const int tid = threadIdx.x;
    const int w = tid >> 6, l = tid & 63;
    const int lq = l & 15, lg = l >> 4;
    const int wm = w >> 1, wn = w & 1;
    const int m0 = blockIdx.y * 128;
    const int n0 = blockIdx.x * 128;

    f32x4 acc[4][4] = {};

    for (int k0 = 0; k0 < 1024; k0 += 32) {
        __syncthreads();
        #pragma unroll
        for (int j = 0; j < 2; ++j) {
            const int c = (j * 4 + w) * 64 + l;
            load_lds16(Yin + (size_t)(m0 + (c >> 2)) * 1024 + k0 + (c & 3) * 8,
                       As + (j * 4 + w) * 512);
            load_lds16(W + (size_t)(n0 + (c >> 2)) * 1024 + k0 + (c & 3) * 8,
                       Bs + (j * 4 + w) * 512);
        }
        __syncthreads();
        short8 af[4], bfr[4];
        #pragma unroll
        for (int mi = 0; mi < 4; ++mi)
            af[mi] = *(const short8*)&As[(wm * 64 + mi * 16 + lq) * 32 + lg * 8];
        #pragma unroll
        for (int ni = 0; ni < 4; ++ni)
            bfr[ni] = *(const short8*)&Bs[(wn * 64 + ni * 16 + lq) * 32 + lg * 8];
        #pragma unroll
        for (int mi = 0; mi < 4; ++mi)
            #pragma unroll
            for (int ni = 0; ni < 4; ++ni)
                acc[mi][ni] = __builtin_amdgcn_mfma_f32_16x16x32_bf16(
                    af[mi], bfr[ni], acc[mi][ni], 0, 0, 0);
    }

    // epilogue: direct fp32 stores from C-fragment layout
    const int mrow0 = m0 + wm * 64;
    const int ncol0 = n0 + wn * 64;
    float bias4[4];
    #pragma unroll
    for (int ni = 0; ni < 4; ++ni)
        bias4[ni] = bias[ncol0 + ni * 16 + lq];

    #pragma unroll
    for (int mi = 0; mi < 4; ++mi)
        #pragma unroll
        for (int r = 0; r < 4; ++r) {
            const size_t rowoff = (size_t)(mrow0 + mi * 16 + lg * 4 + r) * 1024;
            #pragma unroll
            for (int ni = 0; ni < 4; ++ni)
                out[rowoff + ncol0 + ni * 16 + lq] = acc[mi][ni][r] + bias4[ni];
        }
}

// ======================= launcher =======================

extern "C" void kernel_launch(void* const* d_in, const int* in_sizes, int n_in,
                              void* d_out, int out_size, void* d_ws, size_t ws_size,
                              hipStream_t stream) {
    const float* x    = (const float*)d_in[0];
    // d_in[1] (causal mask) applied structurally.
    const float* Wqkv = (const float*)d_in[2];
    const float* bqkv = (const float*)d_in[3];
    const float* Wo   = (const float*)d_in[4];
    const float* bo   = (const float*)d_in[5];

    const size_t QK = (size_t)BB * HH * NN * SS;  // 4,194,304

    uint16_t* Xb  = (uint16_t*)d_ws;
    uint16_t* Wqb = Xb + XE;
    uint16_t* Wob = Wqb + WQE;
    uint16_t* Qb  = Wob + WOE;
    uint16_t* Kb  = Qb + QK;
    uint16_t* Vt  = Kb + QK;
    uint16_t* Yb  = Vt + QK;

    cvt_all<<<(XE + WQE + WOE) / 8 / 256, 256, 0, stream>>>(x, Wqkv, Wo, Xb);
    gemm_qkv<<<dim3(24, 32), 256, 0, stream>>>(Xb, Wqb, bqkv, Qb, Kb, Vt);
    attn_mfma<<<4096, 64, 0, stream>>>(Qb, Kb, Vt, Yb);
    gemm_proj<<<dim3(8, 32), 256, 0, stream>>>(Yb, Wob, bo, (float*)d_out);
}

// Round 12
// 156.286 us; speedup vs baseline: 1.5848x; 1.3050x over previous
//
#include <hip/hip_runtime.h>
#include <hip/hip_bf16.h>
#include <stdint.h>

// Problem constants: B=2, N=2048, D=1024, H=16, head dim s=64.
// Global I/O fp32; internal X/W/Q/K/V/Y intermediates bf16 in d_ws.
// Q is pre-scaled by 0.125*log2e so attention softmax runs in exp2 domain.
#define BB 2
#define NN 2048
#define DD 1024
#define HH 16
#define SS 64

typedef short short8 __attribute__((ext_vector_type(8)));
typedef float f32x4 __attribute__((ext_vector_type(4)));

__device__ __forceinline__ float bf2f(uint16_t u) {
    return __uint_as_float(((uint32_t)u) << 16);
}
__device__ __forceinline__ uint16_t f2bf(float f) {
    uint32_t u = __float_as_uint(f);
    return (uint16_t)((u + 0x7FFFu + ((u >> 16) & 1u)) >> 16);  // RNE
}
__device__ __forceinline__ short8 cvt8(float4 a, float4 b) {
    short8 s;
    s[0] = (short)f2bf(a.x); s[1] = (short)f2bf(a.y);
    s[2] = (short)f2bf(a.z); s[3] = (short)f2bf(a.w);
    s[4] = (short)f2bf(b.x); s[5] = (short)f2bf(b.y);
    s[6] = (short)f2bf(b.z); s[7] = (short)f2bf(b.w);
    return s;
}

__device__ __forceinline__ void load_lds16(const uint16_t* g, uint16_t* l) {
    __builtin_amdgcn_global_load_lds(
        (const __attribute__((address_space(1))) void*)g,
        (__attribute__((address_space(3))) void*)l, 16, 0, 0);
}

#define XE  (4096 * 1024)
#define WQE (3072 * 1024)
#define WOE (1024 * 1024)

// ======================= fused fp32 -> bf16 bulk convert =======================
__global__ __launch_bounds__(256) void cvt_all(
    const float* __restrict__ x, const float* __restrict__ wq,
    const float* __restrict__ wo, uint16_t* __restrict__ dst)
{
    int i = (blockIdx.x * 256 + threadIdx.x) * 8;
    const float* src;
    int off;
    if (i < XE)            { src = x;  off = i; }
    else if (i < XE + WQE) { src = wq; off = i - XE; }
    else                   { src = wo; off = i - XE - WQE; }
    float4 a = *(const float4*)(src + off);
    float4 b = *(const float4*)(src + off + 4);
    *(short8*)(dst + i) = cvt8(a, b);
}

// ======================= QKV projection (MFMA, bf16 in) =======================
// C[4096,3072] = X[4096,1024] @ Wqkv[3072,1024]^T + bqkv
// -> Q bf16 (x0.125*log2e) [bh][2048][64], K bf16 [bh][2048][64], V^T [bh][64][2048]
__global__ __launch_bounds__(256) void gemm_qkv(
    const uint16_t* __restrict__ X, const uint16_t* __restrict__ W,
    const float* __restrict__ bias,
    uint16_t* __restrict__ Qb, uint16_t* __restrict__ Kb, uint16_t* __restrict__ Vt)
{
    __shared__ __align__(16) uint16_t smem[18432];   // 36,864 B
    uint16_t* As = smem;          // [128][32] linear (gload_lds requires)
    uint16_t* Bs = smem + 4096;   // [128][32]

    const int tid = threadIdx.x;
    const int w = tid >> 6, l = tid & 63;
    const int lq = l & 15, lg = l >> 4;
    const int wm = w >> 1, wn = w & 1;
    const int m0 = blockIdx.y * 128;
    const int n0 = blockIdx.x * 128;

    f32x4 acc[4][4] = {};

    for (int k0 = 0; k0 < 1024; k0 += 32) {
        __syncthreads();
        #pragma unroll
        for (int j = 0; j < 2; ++j) {
            const int c = (j * 4 + w) * 64 + l;   // lane's global row/col chunk
            load_lds16(X + (size_t)(m0 + (c >> 2)) * 1024 + k0 + (c & 3) * 8,
                       As + (j * 4 + w) * 512);
            load_lds16(W + (size_t)(n0 + (c >> 2)) * 1024 + k0 + (c & 3) * 8,
                       Bs + (j * 4 + w) * 512);
        }
        __syncthreads();
        short8 af[4], bfr[4];
        #pragma unroll
        for (int mi = 0; mi < 4; ++mi)
            af[mi] = *(const short8*)&As[(wm * 64 + mi * 16 + lq) * 32 + lg * 8];
        #pragma unroll
        for (int ni = 0; ni < 4; ++ni)
            bfr[ni] = *(const short8*)&Bs[(wn * 64 + ni * 16 + lq) * 32 + lg * 8];
        #pragma unroll
        for (int mi = 0; mi < 4; ++mi)
            #pragma unroll
            for (int ni = 0; ni < 4; ++ni)
                acc[mi][ni] = __builtin_amdgcn_mfma_f32_16x16x32_bf16(
                    af[mi], bfr[ni], acc[mi][ni], 0, 0, 0);
    }

    // ---------------- epilogue: bf16 scatter via LDS transpose ----------------
    __syncthreads();  // staging reads complete; reuse smem
    const int part = n0 >> 10;                       // 0=Q 1=K 2=V (uniform)
    const int hh = ((n0 + wn * 64) & 1023) >> 6;     // head (uniform per wave)
    const int mrow0 = m0 + wm * 64;
    const int bh = (mrow0 >> 11) * 16 + hh;
    const int tok0 = mrow0 & 2047;
    // Q pre-scale folds 1/sqrt(64) and log2e for exp2-domain softmax.
    const float scl = (part == 0) ? 0.125f * 1.44269504089f : 1.0f;

    float bias4[4];
    #pragma unroll
    for (int ni = 0; ni < 4; ++ni)
        bias4[ni] = bias[n0 + wn * 64 + ni * 16 + lq];

    uint16_t* T = smem + w * 4608;                   // [64][72] bf16, wave-private
    if (part < 2) {
        #pragma unroll
        for (int mi = 0; mi < 4; ++mi)
            #pragma unroll
            for (int ni = 0; ni < 4; ++ni)
                #pragma unroll
                for (int r = 0; r < 4; ++r)
                    T[(mi * 16 + lg * 4 + r) * 72 + ni * 16 + lq] =
                        f2bf((acc[mi][ni][r] + bias4[ni]) * scl);
    } else {
        #pragma unroll
        for (int mi = 0; mi < 4; ++mi)
            #pragma unroll
            for (int ni = 0; ni < 4; ++ni)
                #pragma unroll
                for (int r = 0; r < 4; ++r)
                    T[(ni * 16 + lq) * 72 + mi * 16 + lg * 4 + r] =
                        f2bf(acc[mi][ni][r] + bias4[ni]);
    }

    const int a0 = l >> 3, b8 = (l & 7) * 8;
    #pragma unroll
    for (int i = 0; i < 8; ++i) {
        int a = i * 8 + a0;
        short8 u = *(short8*)&T[a * 72 + b8];
        uint16_t* p;
        if (part < 2) {
            uint16_t* dst = (part == 0) ? Qb : Kb;
            p = dst + ((size_t)bh * 2048 + tok0 + a) * 64 + b8;
        } else {
            p = Vt + ((size_t)bh * 64 + a) * 2048 + tok0 + b8;
        }
        *(short8*)p = u;
    }
}

// ======================= MFMA flash attention (32 q-rows / wave) =======================
// 2048 blocks x 64 thr. Each wave owns TWO 16-row substrips (32 consecutive
// q-rows) -> every K/V tile load is amortized over 2x the MFMA work and the
// total step count (the latency-bound critical path) halves vs r11.
// bh = id&31 (id%8 -> XCD affinity); blk = 63-(id>>5) descending work.
// kf single-buffered: refilled right after both substrips' QK consume it
// (latency covered by 2x softmax+PV). vv issued at step start.
__device__ __forceinline__ void loadKf(const uint16_t* Kb, int kv0, int lq, int lg,
                                       short8 (&d)[8]) {
    #pragma unroll
    for (int n = 0; n < 4; ++n) {
        const uint16_t* kb = Kb + (size_t)(kv0 + n * 16 + lq) * 64 + lg * 8;
        d[2 * n]     = *(const short8*)kb;
        d[2 * n + 1] = *(const short8*)(kb + 32);
    }
}
__device__ __forceinline__ void loadVf(const uint16_t* Vb, int kv0, int lq, int lg,
                                       short8 (&d)[8]) {
    #pragma unroll
    for (int n = 0; n < 4; ++n) {
        const uint16_t* vb = Vb + (size_t)(n * 16 + lq) * 2048 + kv0 + lg * 8;
        d[2 * n]     = *(const short8*)vb;
        d[2 * n + 1] = *(const short8*)(vb + 32);
    }
}

#define DEFER_THR 11.5f   // ~8 nats in log2 units

__global__ __launch_bounds__(64) void attn_mfma(
    const uint16_t* __restrict__ Q, const uint16_t* __restrict__ K,
    const uint16_t* __restrict__ Vt, uint16_t* __restrict__ Y)
{
    const int id = blockIdx.x;
    const int bh = id & 31;               // id%8 -> stable XCD per bh group
    const int blk = 63 - (id >> 5);       // 32-row q-block, heaviest first
    const int qt = blk >> 1;              // last kv tile index
    const int q0 = blk * 32;

    const int lane = threadIdx.x;
    const int lq = lane & 15;
    const int lg = lane >> 4;

    __shared__ __align__(16) uint16_t Pl[2][16][72];

    const uint16_t* Kb = K + (size_t)bh * (2048 * 64);
    const uint16_t* Vb = Vt + (size_t)bh * (64 * 2048);
    const int b = bh >> 4, h = bh & 15;

    short8 qf[2][2];
    #pragma unroll
    for (int sub = 0; sub < 2; ++sub) {
        const uint16_t* qb = Q + ((size_t)bh * 2048 + q0 + sub * 16 + lq) * 64 + lg * 8;
        qf[sub][0] = *(const short8*)qb;
        qf[sub][1] = *(const short8*)(qb + 32);
    }

    f32x4 y[2][4] = {};
    float m[2][4], lsum[2][4];   // lsum = per-lane partials (reduced in epilogue)
    #pragma unroll
    for (int sub = 0; sub < 2; ++sub)
        #pragma unroll
        for (int r = 0; r < 4; ++r) { m[sub][r] = -INFINITY; lsum[sub][r] = 0.f; }

    short8 kf[8], vv[8];
    loadKf(Kb, 0, lq, lg, kf);

    for (int kt = 0; kt <= qt; ++kt) {
        const int kv0 = kt * 64;
        loadVf(Vb, kv0, lq, lg, vv);

        // ---- QK^T for both substrips (kf fully consumed here) ----
        f32x4 s[2][4];
        __builtin_amdgcn_s_setprio(1);
        #pragma unroll
        for (int sub = 0; sub < 2; ++sub)
            #pragma unroll
            for (int n = 0; n < 4; ++n) {
                f32x4 z = {};
                z = __builtin_amdgcn_mfma_f32_16x16x32_bf16(qf[sub][0], kf[2 * n], z, 0, 0, 0);
                s[sub][n] = __builtin_amdgcn_mfma_f32_16x16x32_bf16(qf[sub][1], kf[2 * n + 1], z, 0, 0, 0);
            }
        __builtin_amdgcn_s_setprio(0);

        // refill K for next tile (covered by 2x softmax+PV below)
        if (kt < qt) loadKf(Kb, kv0 + 64, lq, lg, kf);

        #pragma unroll
        for (int sub = 0; sub < 2; ++sub) {
            if (kt == qt) {
                const int rowb = q0 + sub * 16 + lg * 4;
                #pragma unroll
                for (int n = 0; n < 4; ++n) {
                    int col = kv0 + n * 16 + lq;
                    #pragma unroll
                    for (int r = 0; r < 4; ++r)
                        if (col > rowb + r) s[sub][n][r] = -INFINITY;
                }
            }
            // ---- defer check: per-lane local max + one ballot ----
            float mt[4];
            #pragma unroll
            for (int r = 0; r < 4; ++r)
                mt[r] = fmaxf(fmaxf(s[sub][0][r], s[sub][1][r]),
                              fmaxf(s[sub][2][r], s[sub][3][r]));
            float g = -INFINITY;
            #pragma unroll
            for (int r = 0; r < 4; ++r) g = fmaxf(g, mt[r] - m[sub][r]);
            const bool skip = __all(g <= DEFER_THR);

            if (!skip) {   // rare: full cross-lane max reduce + rescale
                #pragma unroll
                for (int off = 1; off <= 8; off <<= 1)
                    #pragma unroll
                    for (int r = 0; r < 4; ++r)
                        mt[r] = fmaxf(mt[r], __shfl_xor(mt[r], off));
                #pragma unroll
                for (int r = 0; r < 4; ++r) {
                    float mn = fmaxf(m[sub][r], mt[r]);
                    float sc = exp2f(m[sub][r] - mn);
                    m[sub][r] = mn;
                    lsum[sub][r] *= sc;
                    #pragma unroll
                    for (int n = 0; n < 4; ++n)
                        y[sub][n][r] *= sc;
                }
            }

            // ---- exp2 + per-lane psum; P writes split around pa reads ----
            float ps[4] = {0.f, 0.f, 0.f, 0.f};
            #pragma unroll
            for (int n = 0; n < 2; ++n)
                #pragma unroll
                for (int r = 0; r < 4; ++r) {
                    float p = exp2f(s[sub][n][r] - m[sub][r]);
                    ps[r] += p;
                    Pl[sub][lg * 4 + r][n * 16 + lq] = f2bf(p);
                }
            short8 pa0 = *(short8*)&Pl[sub][lq][lg * 8];
            #pragma unroll
            for (int n = 2; n < 4; ++n)
                #pragma unroll
                for (int r = 0; r < 4; ++r) {
                    float p = exp2f(s[sub][n][r] - m[sub][r]);
                    ps[r] += p;
                    Pl[sub][lg * 4 + r][n * 16 + lq] = f2bf(p);
                }
            short8 pa1 = *(short8*)&Pl[sub][lq][lg * 8 + 32];

            #pragma unroll
            for (int r = 0; r < 4; ++r) lsum[sub][r] += ps[r];

            __builtin_amdgcn_s_setprio(1);
            #pragma unroll
            for (int n = 0; n < 4; ++n) {
                y[sub][n] = __builtin_amdgcn_mfma_f32_16x16x32_bf16(pa0, vv[2 * n], y[sub][n], 0, 0, 0);
                y[sub][n] = __builtin_amdgcn_mfma_f32_16x16x32_bf16(pa1, vv[2 * n + 1], y[sub][n], 0, 0, 0);
            }
            __builtin_amdgcn_s_setprio(0);
        }
    }

    // ---- final cross-lane lsum reduce + output ----
    #pragma unroll
    for (int sub = 0; sub < 2; ++sub) {
        #pragma unroll
        for (int off = 1; off <= 8; off <<= 1)
            #pragma unroll
            for (int r = 0; r < 4; ++r)
                lsum[sub][r] += __shfl_xor(lsum[sub][r], off);
        #pragma unroll
        for (int r = 0; r < 4; ++r) {
            float inv = 1.0f / lsum[sub][r];
            int token = b * 2048 + q0 + sub * 16 + lg * 4 + r;
            uint16_t* yrow = Y + (size_t)token * 1024 + h * 64;
            #pragma unroll
            for (int n = 0; n < 4; ++n)
                yrow[n * 16 + lq] = f2bf(y[sub][n][r] * inv);
        }
    }
}

// ======================= output projection (MFMA, fp32 out) =======================
// out[4096,1024] = Y(bf16) @ Wo(bf16)^T + bo
__global__ __launch_bounds__(256) void gemm_proj(
    const uint16_t* __restrict__ Yin, const uint16_t* __restrict__ W,
    const float* __restrict__ bias, float* __restrict__ out)
{
    __shared__ __align__(16) uint16_t smem[8192];   // 2 x [128][32]
    uint16_t* As = smem;
    uint16_t* Bs = smem + 4096;

    const int tid = threadIdx.x;
    const int w = tid >> 6, l = tid & 63;
    const int lq = l & 15, lg = l >> 4;
    const int wm = w >> 1, wn = w & 1;
    const int m0 = blockIdx.y * 128;
    const int n0 = blockIdx.x * 128;

    f32x4 acc[4][4] = {};

    for (int k0 = 0; k0 < 1024; k0 += 32) {
        __syncthreads();
        #pragma unroll
        for (int j = 0; j < 2; ++j) {
            const int c = (j * 4 + w) * 64 + l;
            load_lds16(Yin + (size_t)(m0 + (c >> 2)) * 1024 + k0 + (c & 3) * 8,
                       As + (j * 4 + w) * 512);
            load_lds16(W + (size_t)(n0 + (c >> 2)) * 1024 + k0 + (c & 3) * 8,
                       Bs + (j * 4 + w) * 512);
        }
        __syncthreads();
        short8 af[4], bfr[4];
        #pragma unroll
        for (int mi = 0; mi < 4; ++mi)
            af[mi] = *(const short8*)&As[(wm * 64 + mi * 16 + lq) * 32 + lg * 8];
        #pragma unroll
        for (int ni = 0; ni < 4; ++ni)
            bfr[ni] = *(const short8*)&Bs[(wn * 64 + ni * 16 + lq) * 32 + lg * 8];
        #pragma unroll
        for (int mi = 0; mi < 4; ++mi)
            #pragma unroll
            for (int ni = 0; ni < 4; ++ni)
                acc[mi][ni] = __builtin_amdgcn_mfma_f32_16x16x32_bf16(
                    af[mi], bfr[ni], acc[mi][ni], 0, 0, 0);
    }

    // epilogue: direct fp32 stores from C-fragment layout
    const int mrow0 = m0 + wm * 64;
    const int ncol0 = n0 + wn * 64;
    float bias4[4];
    #pragma unroll
    for (int ni = 0; ni < 4; ++ni)
        bias4[ni] = bias[ncol0 + ni * 16 + lq];

    #pragma unroll
    for (int mi = 0; mi < 4; ++mi)
        #pragma unroll
        for (int r = 0; r < 4; ++r) {
            const size_t rowoff = (size_t)(mrow0 + mi * 16 + lg * 4 + r) * 1024;
            #pragma unroll
            for (int ni = 0; ni < 4; ++ni)
                out[rowoff + ncol0 + ni * 16 + lq] = acc[mi][ni][r] + bias4[ni];
        }
}

// ======================= launcher =======================

extern "C" void kernel_launch(void* const* d_in, const int* in_sizes, int n_in,
                              void* d_out, int out_size, void* d_ws, size_t ws_size,
                              hipStream_t stream) {
    const float* x    = (const float*)d_in[0];
    // d_in[1] (causal mask) applied structurally.
    const float* Wqkv = (const float*)d_in[2];
    const float* bqkv = (const float*)d_in[3];
    const float* Wo   = (const float*)d_in[4];
    const float* bo   = (const float*)d_in[5];

    const size_t QK = (size_t)BB * HH * NN * SS;  // 4,194,304

    uint16_t* Xb  = (uint16_t*)d_ws;
    uint16_t* Wqb = Xb + XE;
    uint16_t* Wob = Wqb + WQE;
    uint16_t* Qb  = Wob + WOE;
    uint16_t* Kb  = Qb + QK;
    uint16_t* Vt  = Kb + QK;
    uint16_t* Yb  = Vt + QK;

    cvt_all<<<(XE + WQE + WOE) / 8 / 256, 256, 0, stream>>>(x, Wqkv, Wo, Xb);
    gemm_qkv<<<dim3(24, 32), 256, 0, stream>>>(Xb, Wqb, bqkv, Qb, Kb, Vt);
    attn_mfma<<<2048, 64, 0, stream>>>(Qb, Kb, Vt, Yb);
    gemm_proj<<<dim3(8, 32), 256, 0, stream>>>(Yb, Wob, bo, (float*)d_out);
}

// Round 13
// 153.491 us; speedup vs baseline: 1.6137x; 1.0182x over previous
//
#include <hip/hip_runtime.h>
#include <hip/hip_bf16.h>
#include <stdint.h>

// Problem constants: B=2, N=2048, D=1024, H=16, head dim s=64.
// Global I/O fp32; internal X/W/Q/K/V/Y intermediates bf16 in d_ws.
// Q is pre-scaled by 0.125*log2e so attention softmax runs in exp2 domain.
#define BB 2
#define NN 2048
#define DD 1024
#define HH 16
#define SS 64

typedef short short8 __attribute__((ext_vector_type(8)));
typedef float f32x4 __attribute__((ext_vector_type(4)));

__device__ __forceinline__ float bf2f(uint16_t u) {
    return __uint_as_float(((uint32_t)u) << 16);
}
__device__ __forceinline__ uint16_t f2bf(float f) {
    uint32_t u = __float_as_uint(f);
    return (uint16_t)((u + 0x7FFFu + ((u >> 16) & 1u)) >> 16);  // RNE
}
__device__ __forceinline__ short8 cvt8(float4 a, float4 b) {
    short8 s;
    s[0] = (short)f2bf(a.x); s[1] = (short)f2bf(a.y);
    s[2] = (short)f2bf(a.z); s[3] = (short)f2bf(a.w);
    s[4] = (short)f2bf(b.x); s[5] = (short)f2bf(b.y);
    s[6] = (short)f2bf(b.z); s[7] = (short)f2bf(b.w);
    return s;
}

__device__ __forceinline__ void load_lds16(const uint16_t* g, uint16_t* l) {
    __builtin_amdgcn_global_load_lds(
        (const __attribute__((address_space(1))) void*)g,
        (__attribute__((address_space(3))) void*)l, 16, 0, 0);
}

#define XE  (4096 * 1024)
#define WQE (3072 * 1024)
#define WOE (1024 * 1024)

// ======================= fused fp32 -> bf16 bulk convert =======================
__global__ __launch_bounds__(256) void cvt_all(
    const float* __restrict__ x, const float* __restrict__ wq,
    const float* __restrict__ wo, uint16_t* __restrict__ dst)
{
    int i = (blockIdx.x * 256 + threadIdx.x) * 8;
    const float* src;
    int off;
    if (i < XE)            { src = x;  off = i; }
    else if (i < XE + WQE) { src = wq; off = i - XE; }
    else                   { src = wo; off = i - XE - WQE; }
    float4 a = *(const float4*)(src + off);
    float4 b = *(const float4*)(src + off + 4);
    *(short8*)(dst + i) = cvt8(a, b);
}

// ======================= QKV projection (MFMA, bf16 in) =======================
// C[4096,3072] = X[4096,1024] @ Wqkv[3072,1024]^T + bqkv
// -> Q bf16 (x0.125*log2e) [bh][2048][64], K bf16 [bh][2048][64], V^T [bh][64][2048]
__global__ __launch_bounds__(256) void gemm_qkv(
    const uint16_t* __restrict__ X, const uint16_t* __restrict__ W,
    const float* __restrict__ bias,
    uint16_t* __restrict__ Qb, uint16_t* __restrict__ Kb, uint16_t* __restrict__ Vt)
{
    __shared__ __align__(16) uint16_t smem[18432];   // 36,864 B
    uint16_t* As = smem;          // [128][32] linear (gload_lds requires)
    uint16_t* Bs = smem + 4096;   // [128][32]

    const int tid = threadIdx.x;
    const int w = tid >> 6, l = tid & 63;
    const int lq = l & 15, lg = l >> 4;
    const int wm = w >> 1, wn = w & 1;
    const int m0 = blockIdx.y * 128;
    const int n0 = blockIdx.x * 128;

    f32x4 acc[4][4] = {};

    for (int k0 = 0; k0 < 1024; k0 += 32) {
        __syncthreads();
        #pragma unroll
        for (int j = 0; j < 2; ++j) {
            const int c = (j * 4 + w) * 64 + l;   // lane's global row/col chunk
            load_lds16(X + (size_t)(m0 + (c >> 2)) * 1024 + k0 + (c & 3) * 8,
                       As + (j * 4 + w) * 512);
            load_lds16(W + (size_t)(n0 + (c >> 2)) * 1024 + k0 + (c & 3) * 8,
                       Bs + (j * 4 + w) * 512);
        }
        __syncthreads();
        short8 af[4], bfr[4];
        #pragma unroll
        for (int mi = 0; mi < 4; ++mi)
            af[mi] = *(const short8*)&As[(wm * 64 + mi * 16 + lq) * 32 + lg * 8];
        #pragma unroll
        for (int ni = 0; ni < 4; ++ni)
            bfr[ni] = *(const short8*)&Bs[(wn * 64 + ni * 16 + lq) * 32 + lg * 8];
        #pragma unroll
        for (int mi = 0; mi < 4; ++mi)
            #pragma unroll
            for (int ni = 0; ni < 4; ++ni)
                acc[mi][ni] = __builtin_amdgcn_mfma_f32_16x16x32_bf16(
                    af[mi], bfr[ni], acc[mi][ni], 0, 0, 0);
    }

    // ---------------- epilogue: bf16 scatter via LDS transpose ----------------
    __syncthreads();  // staging reads complete; reuse smem
    const int part = n0 >> 10;                       // 0=Q 1=K 2=V (uniform)
    const int hh = ((n0 + wn * 64) & 1023) >> 6;     // head (uniform per wave)
    const int mrow0 = m0 + wm * 64;
    const int bh = (mrow0 >> 11) * 16 + hh;
    const int tok0 = mrow0 & 2047;
    // Q pre-scale folds 1/sqrt(64) and log2e for exp2-domain softmax.
    const float scl = (part == 0) ? 0.125f * 1.44269504089f : 1.0f;

    float bias4[4];
    #pragma unroll
    for (int ni = 0; ni < 4; ++ni)
        bias4[ni] = bias[n0 + wn * 64 + ni * 16 + lq];

    uint16_t* T = smem + w * 4608;                   // [64][72] bf16, wave-private
    if (part < 2) {
        #pragma unroll
        for (int mi = 0; mi < 4; ++mi)
            #pragma unroll
            for (int ni = 0; ni < 4; ++ni)
                #pragma unroll
                for (int r = 0; r < 4; ++r)
                    T[(mi * 16 + lg * 4 + r) * 72 + ni * 16 + lq] =
                        f2bf((acc[mi][ni][r] + bias4[ni]) * scl);
    } else {
        #pragma unroll
        for (int mi = 0; mi < 4; ++mi)
            #pragma unroll
            for (int ni = 0; ni < 4; ++ni)
                #pragma unroll
                for (int r = 0; r < 4; ++r)
                    T[(ni * 16 + lq) * 72 + mi * 16 + lg * 4 + r] =
                        f2bf(acc[mi][ni][r] + bias4[ni]);
    }

    const int a0 = l >> 3, b8 = (l & 7) * 8;
    #pragma unroll
    for (int i = 0; i < 8; ++i) {
        int a = i * 8 + a0;
        short8 u = *(short8*)&T[a * 72 + b8];
        uint16_t* p;
        if (part < 2) {
            uint16_t* dst = (part == 0) ? Qb : Kb;
            p = dst + ((size_t)bh * 2048 + tok0 + a) * 64 + b8;
        } else {
            p = Vt + ((size_t)bh * 64 + a) * 2048 + tok0 + b8;
        }
        *(short8*)p = u;
    }
}

// ======================= MFMA flash attention (swapped QK, 32 q-rows / wave) ====
// 2048 blocks x 64 thr. Swapped QK^T: z = mfma(K,Q) -> lane holds P[kv...][q=lq],
// so softmax state m/lsum is SCALAR per lane; P pack = 8 cvt_pk + 4 ds_write_b64
// (was 48 VALU cvt + 32 ds_write_b16). bh = id&31 (XCD affinity), blk descending.
__device__ __forceinline__ void loadKf(const uint16_t* Kb, int kv0, int lq, int lg,
                                       short8 (&d)[8]) {
    #pragma unroll
    for (int n = 0; n < 4; ++n) {
        const uint16_t* kb = Kb + (size_t)(kv0 + n * 16 + lq) * 64 + lg * 8;
        d[2 * n]     = *(const short8*)kb;
        d[2 * n + 1] = *(const short8*)(kb + 32);
    }
}
__device__ __forceinline__ void loadVf(const uint16_t* Vb, int kv0, int lq, int lg,
                                       short8 (&d)[8]) {
    #pragma unroll
    for (int n = 0; n < 4; ++n) {
        const uint16_t* vb = Vb + (size_t)(n * 16 + lq) * 2048 + kv0 + lg * 8;
        d[2 * n]     = *(const short8*)vb;
        d[2 * n + 1] = *(const short8*)(vb + 32);
    }
}

#define DEFER_THR 11.5f   // ~8 nats in log2 units

__global__ __launch_bounds__(64) void attn_mfma(
    const uint16_t* __restrict__ Q, const uint16_t* __restrict__ K,
    const uint16_t* __restrict__ Vt, uint16_t* __restrict__ Y)
{
    const int id = blockIdx.x;
    const int bh = id & 31;               // id%8 -> stable XCD per bh group
    const int blk = 63 - (id >> 5);       // 32-row q-block, heaviest first
    const int qt = blk >> 1;              // last kv tile index
    const int q0 = blk * 32;

    const int lane = threadIdx.x;
    const int lq = lane & 15;
    const int lg = lane >> 4;

    __shared__ __align__(16) uint16_t Pl[2][16][72];

    const uint16_t* Kb = K + (size_t)bh * (2048 * 64);
    const uint16_t* Vb = Vt + (size_t)bh * (64 * 2048);
    const int b = bh >> 4, h = bh & 15;

    short8 qf[2][2];
    #pragma unroll
    for (int sub = 0; sub < 2; ++sub) {
        const uint16_t* qb = Q + ((size_t)bh * 2048 + q0 + sub * 16 + lq) * 64 + lg * 8;
        qf[sub][0] = *(const short8*)qb;
        qf[sub][1] = *(const short8*)(qb + 32);
    }

    f32x4 y[2][4] = {};
    float m[2]    = {-INFINITY, -INFINITY};   // scalar state: lane's q = q0s + lq
    float lsum[2] = {0.f, 0.f};               // per-lane partial (lane's kv subset)

    short8 kf[8], vv[8];
    loadKf(Kb, 0, lq, lg, kf);

    for (int kt = 0; kt <= qt; ++kt) {
        const int kv0 = kt * 64;
        loadVf(Vb, kv0, lq, lg, vv);

        // ---- swapped QK^T: z[sub][n][r] = S[q0s+lq][kv0 + n*16 + lg*4 + r] ----
        f32x4 z[2][4];
        __builtin_amdgcn_s_setprio(1);
        #pragma unroll
        for (int sub = 0; sub < 2; ++sub)
            #pragma unroll
            for (int n = 0; n < 4; ++n) {
                f32x4 t = {};
                t = __builtin_amdgcn_mfma_f32_16x16x32_bf16(kf[2 * n], qf[sub][0], t, 0, 0, 0);
                z[sub][n] = __builtin_amdgcn_mfma_f32_16x16x32_bf16(kf[2 * n + 1], qf[sub][1], t, 0, 0, 0);
            }
        __builtin_amdgcn_s_setprio(0);

        // refill K for next tile (covered by 2x softmax+PV below)
        if (kt < qt) loadKf(Kb, kv0 + 64, lq, lg, kf);

        #pragma unroll
        for (int sub = 0; sub < 2; ++sub) {
            if (kt == qt) {
                const int qrow = q0 + sub * 16 + lq;
                #pragma unroll
                for (int n = 0; n < 4; ++n) {
                    const int kvb = kv0 + n * 16 + lg * 4;
                    #pragma unroll
                    for (int r = 0; r < 4; ++r)
                        if (kvb + r > qrow) z[sub][n][r] = -INFINITY;
                }
            }
            // ---- per-lane partial max over this lane's 16 kv ----
            float mt = -INFINITY;
            #pragma unroll
            for (int n = 0; n < 4; ++n)
                #pragma unroll
                for (int r = 0; r < 4; ++r)
                    mt = fmaxf(mt, z[sub][n][r]);
            const bool skip = __all(mt - m[sub] <= DEFER_THR);

            if (!skip) {   // rare: reduce across the 4 lg-groups (same q = lq)
                float mf = fmaxf(mt, __shfl_xor(mt, 16));
                mf = fmaxf(mf, __shfl_xor(mf, 32));
                const float mn = fmaxf(m[sub], mf);
                const float sc = exp2f(m[sub] - mn);
                m[sub] = mn;
                lsum[sub] *= sc;
                float scy[4];
                #pragma unroll
                for (int r = 0; r < 4; ++r) scy[r] = __shfl(sc, lg * 4 + r);
                #pragma unroll
                for (int n = 0; n < 4; ++n)
                    #pragma unroll
                    for (int r = 0; r < 4; ++r)
                        y[sub][n][r] *= scy[r];
            }

            // ---- exp2, pack pairs via cvt_pk, 4x ds_write_b64 ----
            float ps = 0.f;
            uint32_t pk0[4], pk1[4];
            #pragma unroll
            for (int n = 0; n < 4; ++n) {
                float e0 = exp2f(z[sub][n][0] - m[sub]);
                float e1 = exp2f(z[sub][n][1] - m[sub]);
                float e2 = exp2f(z[sub][n][2] - m[sub]);
                float e3 = exp2f(z[sub][n][3] - m[sub]);
                ps += (e0 + e1) + (e2 + e3);
                asm("v_cvt_pk_bf16_f32 %0, %1, %2" : "=v"(pk0[n]) : "v"(e0), "v"(e1));
                asm("v_cvt_pk_bf16_f32 %0, %1, %2" : "=v"(pk1[n]) : "v"(e2), "v"(e3));
            }
            lsum[sub] += ps;
            #pragma unroll
            for (int n = 0; n < 4; ++n) {
                uint2 u; u.x = pk0[n]; u.y = pk1[n];
                *(uint2*)&Pl[sub][lq][n * 16 + lg * 4] = u;   // row q=lq, kv off n*16+lg*4
            }

            short8 pa0 = *(short8*)&Pl[sub][lq][lg * 8];        // kv 0..31 slice
            short8 pa1 = *(short8*)&Pl[sub][lq][lg * 8 + 32];   // kv 32..63 slice
            __builtin_amdgcn_s_setprio(1);
            #pragma unroll
            for (int n = 0; n < 4; ++n) {
                y[sub][n] = __builtin_amdgcn_mfma_f32_16x16x32_bf16(pa0, vv[2 * n], y[sub][n], 0, 0, 0);
                y[sub][n] = __builtin_amdgcn_mfma_f32_16x16x32_bf16(pa1, vv[2 * n + 1], y[sub][n], 0, 0, 0);
            }
            __builtin_amdgcn_s_setprio(0);
        }
    }

    // ---- epilogue: lsum reduce (2 rounds), redistribute inv to y-rows ----
    #pragma unroll
    for (int sub = 0; sub < 2; ++sub) {
        float ls = lsum[sub];
        ls += __shfl_xor(ls, 16);
        ls += __shfl_xor(ls, 32);
        const float inv = 1.0f / ls;          // for q = q0s + lq
        float invy[4];
        #pragma unroll
        for (int r = 0; r < 4; ++r) invy[r] = __shfl(inv, lg * 4 + r);
        #pragma unroll
        for (int r = 0; r < 4; ++r) {
            int token = b * 2048 + q0 + sub * 16 + lg * 4 + r;
            uint16_t* yrow = Y + (size_t)token * 1024 + h * 64;
            #pragma unroll
            for (int n = 0; n < 4; ++n)
                yrow[n * 16 + lq] = f2bf(y[sub][n][r] * invy[r]);
        }
    }
}

// ======================= output projection (MFMA, fp32 out) =======================
// out[4096,1024] = Y(bf16) @ Wo(bf16)^T + bo
__global__ __launch_bounds__(256) void gemm_proj(
    const uint16_t* __restrict__ Yin, const uint16_t* __restrict__ W,
    const float* __restrict__ bias, float* __restrict__ out)
{
    __shared__ __align__(16) uint16_t smem[8192];   // 2 x [128][32]
    uint16_t* As = smem;
    uint16_t* Bs = smem + 4096;

    const int tid = threadIdx.x;
    const int w = tid >> 6, l = tid & 63;
    const int lq = l & 15, lg = l >> 4;
    const int wm = w >> 1, wn = w & 1;
    const int m0 = blockIdx.y * 128;
    const int n0 = blockIdx.x * 128;

    f32x4 acc[4][4] = {};

    for (int k0 = 0; k0 < 1024; k0 += 32) {
        __syncthreads();
        #pragma unroll
        for (int j = 0; j < 2; ++j) {
            const int c = (j * 4 + w) * 64 + l;
            load_lds16(Yin + (size_t)(m0 + (c >> 2)) * 1024 + k0 + (c & 3) * 8,
                       As + (j * 4 + w) * 512);
            load_lds16(W + (size_t)(n0 + (c >> 2)) * 1024 + k0 + (c & 3) * 8,
                       Bs + (j * 4 + w) * 512);
        }
        __syncthreads();
        short8 af[4], bfr[4];
        #pragma unroll
        for (int mi = 0; mi < 4; ++mi)
            af[mi] = *(const short8*)&As[(wm * 64 + mi * 16 + lq) * 32 + lg * 8];
        #pragma unroll
        for (int ni = 0; ni < 4; ++ni)
            bfr[ni] = *(const short8*)&Bs[(wn * 64 + ni * 16 + lq) * 32 + lg * 8];
        #pragma unroll
        for (int mi = 0; mi < 4; ++mi)
            #pragma unroll
            for (int ni = 0; ni < 4; ++ni)
                acc[mi][ni] = __builtin_amdgcn_mfma_f32_16x16x32_bf16(
                    af[mi], bfr[ni], acc[mi][ni], 0, 0, 0);
    }

    // epilogue: direct fp32 stores from C-fragment layout
    const int mrow0 = m0 + wm * 64;
    const int ncol0 = n0 + wn * 64;
    float bias4[4];
    #pragma unroll
    for (int ni = 0; ni < 4; ++ni)
        bias4[ni] = bias[ncol0 + ni * 16 + lq];

    #pragma unroll
    for (int mi = 0; mi < 4; ++mi)
        #pragma unroll
        for (int r = 0; r < 4; ++r) {
            const size_t rowoff = (size_t)(mrow0 + mi * 16 + lg * 4 + r) * 1024;
            #pragma unroll
            for (int ni = 0; ni < 4; ++ni)
                out[rowoff + ncol0 + ni * 16 + lq] = acc[mi][ni][r] + bias4[ni];
        }
}

// ======================= launcher =======================

extern "C" void kernel_launch(void* const* d_in, const int* in_sizes, int n_in,
                              void* d_out, int out_size, void* d_ws, size_t ws_size,
                              hipStream_t stream) {
    const float* x    = (const float*)d_in[0];
    // d_in[1] (causal mask) applied structurally.
    const float* Wqkv = (const float*)d_in[2];
    const float* bqkv = (const float*)d_in[3];
    const float* Wo   = (const float*)d_in[4];
    const float* bo   = (const float*)d_in[5];

    const size_t QK = (size_t)BB * HH * NN * SS;  // 4,194,304

    uint16_t* Xb  = (uint16_t*)d_ws;
    uint16_t* Wqb = Xb + XE;
    uint16_t* Wob = Wqb + WQE;
    uint16_t* Qb  = Wob + WOE;
    uint16_t* Kb  = Qb + QK;
    uint16_t* Vt  = Kb + QK;
    uint16_t* Yb  = Vt + QK;

    cvt_all<<<(XE + WQE + WOE) / 8 / 256, 256, 0, stream>>>(x, Wqkv, Wo, Xb);
    gemm_qkv<<<dim3(24, 32), 256, 0, stream>>>(Xb, Wqb, bqkv, Qb, Kb, Vt);
    attn_mfma<<<2048, 64, 0, stream>>>(Qb, Kb, Vt, Yb);
    gemm_proj<<<dim3(8, 32), 256, 0, stream>>>(Yb, Wob, bo, (float*)d_out);
}

// Round 14
// 149.918 us; speedup vs baseline: 1.6521x; 1.0238x over previous
//
#include <hip/hip_runtime.h>
#include <hip/hip_bf16.h>
#include <stdint.h>

// Problem constants: B=2, N=2048, D=1024, H=16, head dim s=64.
// Global I/O fp32; internal X/W/Q/K/V/Y intermediates bf16 in d_ws.
// Q is pre-scaled by 0.125*log2e so attention softmax runs in exp2 domain.
#define BB 2
#define NN 2048
#define DD 1024
#define HH 16
#define SS 64

typedef short short8 __attribute__((ext_vector_type(8)));
typedef float f32x4 __attribute__((ext_vector_type(4)));

__device__ __forceinline__ float bf2f(uint16_t u) {
    return __uint_as_float(((uint32_t)u) << 16);
}
__device__ __forceinline__ uint16_t f2bf(float f) {
    uint32_t u = __float_as_uint(f);
    return (uint16_t)((u + 0x7FFFu + ((u >> 16) & 1u)) >> 16);  // RNE
}
__device__ __forceinline__ short8 cvt8(float4 a, float4 b) {
    short8 s;
    s[0] = (short)f2bf(a.x); s[1] = (short)f2bf(a.y);
    s[2] = (short)f2bf(a.z); s[3] = (short)f2bf(a.w);
    s[4] = (short)f2bf(b.x); s[5] = (short)f2bf(b.y);
    s[6] = (short)f2bf(b.z); s[7] = (short)f2bf(b.w);
    return s;
}

__device__ __forceinline__ void load_lds16(const uint16_t* g, uint16_t* l) {
    __builtin_amdgcn_global_load_lds(
        (const __attribute__((address_space(1))) void*)g,
        (__attribute__((address_space(3))) void*)l, 16, 0, 0);
}

#define XE  (4096 * 1024)
#define WQE (3072 * 1024)
#define WOE (1024 * 1024)

// ======================= fused fp32 -> bf16 bulk convert =======================
__global__ __launch_bounds__(256) void cvt_all(
    const float* __restrict__ x, const float* __restrict__ wq,
    const float* __restrict__ wo, uint16_t* __restrict__ dst)
{
    int i = (blockIdx.x * 256 + threadIdx.x) * 8;
    const float* src;
    int off;
    if (i < XE)            { src = x;  off = i; }
    else if (i < XE + WQE) { src = wq; off = i - XE; }
    else                   { src = wo; off = i - XE - WQE; }
    float4 a = *(const float4*)(src + off);
    float4 b = *(const float4*)(src + off + 4);
    *(short8*)(dst + i) = cvt8(a, b);
}

// ======================= QKV projection (MFMA, bf16 in) =======================
// C[4096,3072] = X[4096,1024] @ Wqkv[3072,1024]^T + bqkv
// -> Q bf16 (x0.125*log2e) [bh][2048][64], K bf16 [bh][2048][64], V^T [bh][64][2048]
__global__ __launch_bounds__(256) void gemm_qkv(
    const uint16_t* __restrict__ X, const uint16_t* __restrict__ W,
    const float* __restrict__ bias,
    uint16_t* __restrict__ Qb, uint16_t* __restrict__ Kb, uint16_t* __restrict__ Vt)
{
    __shared__ __align__(16) uint16_t smem[18432];   // 36,864 B
    uint16_t* As = smem;          // [128][32] linear (gload_lds requires)
    uint16_t* Bs = smem + 4096;   // [128][32]

    const int tid = threadIdx.x;
    const int w = tid >> 6, l = tid & 63;
    const int lq = l & 15, lg = l >> 4;
    const int wm = w >> 1, wn = w & 1;
    const int m0 = blockIdx.y * 128;
    const int n0 = blockIdx.x * 128;

    f32x4 acc[4][4] = {};

    for (int k0 = 0; k0 < 1024; k0 += 32) {
        __syncthreads();
        #pragma unroll
        for (int j = 0; j < 2; ++j) {
            const int c = (j * 4 + w) * 64 + l;   // lane's global row/col chunk
            load_lds16(X + (size_t)(m0 + (c >> 2)) * 1024 + k0 + (c & 3) * 8,
                       As + (j * 4 + w) * 512);
            load_lds16(W + (size_t)(n0 + (c >> 2)) * 1024 + k0 + (c & 3) * 8,
                       Bs + (j * 4 + w) * 512);
        }
        __syncthreads();
        short8 af[4], bfr[4];
        #pragma unroll
        for (int mi = 0; mi < 4; ++mi)
            af[mi] = *(const short8*)&As[(wm * 64 + mi * 16 + lq) * 32 + lg * 8];
        #pragma unroll
        for (int ni = 0; ni < 4; ++ni)
            bfr[ni] = *(const short8*)&Bs[(wn * 64 + ni * 16 + lq) * 32 + lg * 8];
        #pragma unroll
        for (int mi = 0; mi < 4; ++mi)
            #pragma unroll
            for (int ni = 0; ni < 4; ++ni)
                acc[mi][ni] = __builtin_amdgcn_mfma_f32_16x16x32_bf16(
                    af[mi], bfr[ni], acc[mi][ni], 0, 0, 0);
    }

    // ---------------- epilogue: bf16 scatter via LDS transpose ----------------
    __syncthreads();  // staging reads complete; reuse smem
    const int part = n0 >> 10;                       // 0=Q 1=K 2=V (uniform)
    const int hh = ((n0 + wn * 64) & 1023) >> 6;     // head (uniform per wave)
    const int mrow0 = m0 + wm * 64;
    const int bh = (mrow0 >> 11) * 16 + hh;
    const int tok0 = mrow0 & 2047;
    // Q pre-scale folds 1/sqrt(64) and log2e for exp2-domain softmax.
    const float scl = (part == 0) ? 0.125f * 1.44269504089f : 1.0f;

    float bias4[4];
    #pragma unroll
    for (int ni = 0; ni < 4; ++ni)
        bias4[ni] = bias[n0 + wn * 64 + ni * 16 + lq];

    uint16_t* T = smem + w * 4608;                   // [64][72] bf16, wave-private
    if (part < 2) {
        #pragma unroll
        for (int mi = 0; mi < 4; ++mi)
            #pragma unroll
            for (int ni = 0; ni < 4; ++ni)
                #pragma unroll
                for (int r = 0; r < 4; ++r)
                    T[(mi * 16 + lg * 4 + r) * 72 + ni * 16 + lq] =
                        f2bf((acc[mi][ni][r] + bias4[ni]) * scl);
    } else {
        #pragma unroll
        for (int mi = 0; mi < 4; ++mi)
            #pragma unroll
            for (int ni = 0; ni < 4; ++ni)
                #pragma unroll
                for (int r = 0; r < 4; ++r)
                    T[(ni * 16 + lq) * 72 + mi * 16 + lg * 4 + r] =
                        f2bf(acc[mi][ni][r] + bias4[ni]);
    }

    const int a0 = l >> 3, b8 = (l & 7) * 8;
    #pragma unroll
    for (int i = 0; i < 8; ++i) {
        int a = i * 8 + a0;
        short8 u = *(short8*)&T[a * 72 + b8];
        uint16_t* p;
        if (part < 2) {
            uint16_t* dst = (part == 0) ? Qb : Kb;
            p = dst + ((size_t)bh * 2048 + tok0 + a) * 64 + b8;
        } else {
            p = Vt + ((size_t)bh * 64 + a) * 2048 + tok0 + b8;
        }
        *(short8*)p = u;
    }
}

// ======================= MFMA flash attention (kv-split, 2 waves/block) =========
// 2048 blocks x 128 thr. Both waves share the same 32 q-rows; wave w handles
// kv tiles kt === w (mod 2) -> longest wave 32 -> 16 steps, wave count 2x
// (4 waves/SIMD at ~112 VGPR). Exact merge via online-softmax algebra in LDS.
// Swapped QK^T (scalar m/lsum per lane), exp2 domain, per-lane defer ballot.
__device__ __forceinline__ void loadKf(const uint16_t* Kb, int kv0, int lq, int lg,
                                       short8 (&d)[8]) {
    #pragma unroll
    for (int n = 0; n < 4; ++n) {
        const uint16_t* kb = Kb + (size_t)(kv0 + n * 16 + lq) * 64 + lg * 8;
        d[2 * n]     = *(const short8*)kb;
        d[2 * n + 1] = *(const short8*)(kb + 32);
    }
}
__device__ __forceinline__ void loadVf(const uint16_t* Vb, int kv0, int lq, int lg,
                                       short8 (&d)[8]) {
    #pragma unroll
    for (int n = 0; n < 4; ++n) {
        const uint16_t* vb = Vb + (size_t)(n * 16 + lq) * 2048 + kv0 + lg * 8;
        d[2 * n]     = *(const short8*)vb;
        d[2 * n + 1] = *(const short8*)(vb + 32);
    }
}

#define DEFER_THR 11.5f   // ~8 nats in log2 units

__global__ __launch_bounds__(128) void attn_mfma(
    const uint16_t* __restrict__ Q, const uint16_t* __restrict__ K,
    const uint16_t* __restrict__ Vt, uint16_t* __restrict__ Y)
{
    const int id = blockIdx.x;
    const int bh = id & 31;               // id%8 -> stable XCD per bh group
    const int blk = 63 - (id >> 5);       // 32-row q-block, heaviest first
    const int qt = blk >> 1;              // last kv tile index
    const int q0 = blk * 32;

    const int wv = threadIdx.x >> 6;      // 0 or 1: kv-parity this wave owns
    const int lane = threadIdx.x & 63;
    const int lq = lane & 15;
    const int lg = lane >> 4;

    __shared__ __align__(16) uint16_t Pl[2][2][16][72];  // [wave][sub]
    __shared__ float  My[32][68];                        // wave1 partial y (padded)
    __shared__ float2 Mml[32];                           // wave1 (m, lsum) per q-row

    const uint16_t* Kb = K + (size_t)bh * (2048 * 64);
    const uint16_t* Vb = Vt + (size_t)bh * (64 * 2048);
    const int b = bh >> 4, h = bh & 15;

    short8 qf[2][2];
    #pragma unroll
    for (int sub = 0; sub < 2; ++sub) {
        const uint16_t* qb = Q + ((size_t)bh * 2048 + q0 + sub * 16 + lq) * 64 + lg * 8;
        qf[sub][0] = *(const short8*)qb;
        qf[sub][1] = *(const short8*)(qb + 32);
    }

    f32x4 y[2][4] = {};
    float m[2]    = {-INFINITY, -INFINITY};   // scalar state: lane's q = q0s + lq
    float lsum[2] = {0.f, 0.f};               // per-lane partial

    short8 kf[8], vv[8];
    loadKf(Kb, wv * 64, lq, lg, kf);          // first owned tile (always in-bounds)

    for (int kt = wv; kt <= qt; kt += 2) {
        const int kv0 = kt * 64;
        loadVf(Vb, kv0, lq, lg, vv);

        // ---- swapped QK^T: z[sub][n][r] = S[q0s+lq][kv0 + n*16 + lg*4 + r] ----
        f32x4 z[2][4];
        __builtin_amdgcn_s_setprio(1);
        #pragma unroll
        for (int sub = 0; sub < 2; ++sub)
            #pragma unroll
            for (int n = 0; n < 4; ++n) {
                f32x4 t = {};
                t = __builtin_amdgcn_mfma_f32_16x16x32_bf16(kf[2 * n], qf[sub][0], t, 0, 0, 0);
                z[sub][n] = __builtin_amdgcn_mfma_f32_16x16x32_bf16(kf[2 * n + 1], qf[sub][1], t, 0, 0, 0);
            }
        __builtin_amdgcn_s_setprio(0);

        // refill K for this wave's next tile (kt+2)
        if (kt + 2 <= qt) loadKf(Kb, kv0 + 128, lq, lg, kf);

        #pragma unroll
        for (int sub = 0; sub < 2; ++sub) {
            if (kt == qt) {
                const int qrow = q0 + sub * 16 + lq;
                #pragma unroll
                for (int n = 0; n < 4; ++n) {
                    const int kvb = kv0 + n * 16 + lg * 4;
                    #pragma unroll
                    for (int r = 0; r < 4; ++r)
                        if (kvb + r > qrow) z[sub][n][r] = -INFINITY;
                }
            }
            // ---- per-lane partial max + one ballot ----
            float mt = -INFINITY;
            #pragma unroll
            for (int n = 0; n < 4; ++n)
                #pragma unroll
                for (int r = 0; r < 4; ++r)
                    mt = fmaxf(mt, z[sub][n][r]);
            const bool skip = __all(mt - m[sub] <= DEFER_THR);

            if (!skip) {   // rare: reduce across the 4 lg-groups (same q = lq)
                float mf = fmaxf(mt, __shfl_xor(mt, 16));
                mf = fmaxf(mf, __shfl_xor(mf, 32));
                const float mn = fmaxf(m[sub], mf);
                const float sc = exp2f(m[sub] - mn);
                m[sub] = mn;
                lsum[sub] *= sc;
                float scy[4];
                #pragma unroll
                for (int r = 0; r < 4; ++r) scy[r] = __shfl(sc, lg * 4 + r);
                #pragma unroll
                for (int n = 0; n < 4; ++n)
                    #pragma unroll
                    for (int r = 0; r < 4; ++r)
                        y[sub][n][r] *= scy[r];
            }

            // ---- exp2, pack pairs via cvt_pk, 4x ds_write_b64 ----
            float ps = 0.f;
            uint32_t pk0[4], pk1[4];
            #pragma unroll
            for (int n = 0; n < 4; ++n) {
                float e0 = exp2f(z[sub][n][0] - m[sub]);
                float e1 = exp2f(z[sub][n][1] - m[sub]);
                float e2 = exp2f(z[sub][n][2] - m[sub]);
                float e3 = exp2f(z[sub][n][3] - m[sub]);
                ps += (e0 + e1) + (e2 + e3);
                asm("v_cvt_pk_bf16_f32 %0, %1, %2" : "=v"(pk0[n]) : "v"(e0), "v"(e1));
                asm("v_cvt_pk_bf16_f32 %0, %1, %2" : "=v"(pk1[n]) : "v"(e2), "v"(e3));
            }
            lsum[sub] += ps;
            #pragma unroll
            for (int n = 0; n < 4; ++n) {
                uint2 u; u.x = pk0[n]; u.y = pk1[n];
                *(uint2*)&Pl[wv][sub][lq][n * 16 + lg * 4] = u;
            }

            short8 pa0 = *(short8*)&Pl[wv][sub][lq][lg * 8];
            short8 pa1 = *(short8*)&Pl[wv][sub][lq][lg * 8 + 32];
            __builtin_amdgcn_s_setprio(1);
            #pragma unroll
            for (int n = 0; n < 4; ++n) {
                y[sub][n] = __builtin_amdgcn_mfma_f32_16x16x32_bf16(pa0, vv[2 * n], y[sub][n], 0, 0, 0);
                y[sub][n] = __builtin_amdgcn_mfma_f32_16x16x32_bf16(pa1, vv[2 * n + 1], y[sub][n], 0, 0, 0);
            }
            __builtin_amdgcn_s_setprio(0);
        }
    }

    // ---- reduce per-lane lsum across lg groups (both waves) ----
    float ls[2];
    #pragma unroll
    for (int sub = 0; sub < 2; ++sub) {
        float t = lsum[sub];
        t += __shfl_xor(t, 16);
        t += __shfl_xor(t, 32);
        ls[sub] = t;
    }

    // ---- merge: wave1 posts partials; wave0 combines + writes ----
    if (wv == 1) {
        #pragma unroll
        for (int sub = 0; sub < 2; ++sub) {
            #pragma unroll
            for (int n = 0; n < 4; ++n)
                #pragma unroll
                for (int r = 0; r < 4; ++r)
                    My[sub * 16 + lg * 4 + r][n * 16 + lq] = y[sub][n][r];
            if (lg == 0) Mml[sub * 16 + lq] = make_float2(m[sub], ls[sub]);
        }
    }
    __syncthreads();
    if (wv == 0) {
        #pragma unroll
        for (int sub = 0; sub < 2; ++sub) {
            float2 o = Mml[sub * 16 + lq];
            const float m1 = o.x, l1 = o.y;
            const float mx = fmaxf(m[sub], m1);
            const float w0 = exp2f(m[sub] - mx);
            const float w1 = exp2f(m1 - mx);
            const float inv = 1.0f / (ls[sub] * w0 + l1 * w1);
            const float f0 = w0 * inv, f1 = w1 * inv;
            float f0r[4], f1r[4];
            #pragma unroll
            for (int r = 0; r < 4; ++r) {
                f0r[r] = __shfl(f0, lg * 4 + r);
                f1r[r] = __shfl(f1, lg * 4 + r);
            }
            #pragma unroll
            for (int r = 0; r < 4; ++r) {
                int token = b * 2048 + q0 + sub * 16 + lg * 4 + r;
                uint16_t* yrow = Y + (size_t)token * 1024 + h * 64;
                #pragma unroll
                for (int n = 0; n < 4; ++n) {
                    float val = y[sub][n][r] * f0r[r] +
                                My[sub * 16 + lg * 4 + r][n * 16 + lq] * f1r[r];
                    yrow[n * 16 + lq] = f2bf(val);
                }
            }
        }
    }
}

// ======================= output projection (MFMA, fp32 out) =======================
// out[4096,1024] = Y(bf16) @ Wo(bf16)^T + bo
__global__ __launch_bounds__(256) void gemm_proj(
    const uint16_t* __restrict__ Yin, const uint16_t* __restrict__ W,
    const float* __restrict__ bias, float* __restrict__ out)
{
    __shared__ __align__(16) uint16_t smem[8192];   // 2 x [128][32]
    uint16_t* As = smem;
    uint16_t* Bs = smem + 4096;

    const int tid = threadIdx.x;
    const int w = tid >> 6, l = tid & 63;
    const int lq = l & 15, lg = l >> 4;
    const int wm = w >> 1, wn = w & 1;
    const int m0 = blockIdx.y * 128;
    const int n0 = blockIdx.x * 128;

    f32x4 acc[4][4] = {};

    for (int k0 = 0; k0 < 1024; k0 += 32) {
        __syncthreads();
        #pragma unroll
        for (int j = 0; j < 2; ++j) {
            const int c = (j * 4 + w) * 64 + l;
            load_lds16(Yin + (size_t)(m0 + (c >> 2)) * 1024 + k0 + (c & 3) * 8,
                       As + (j * 4 + w) * 512);
            load_lds16(W + (size_t)(n0 + (c >> 2)) * 1024 + k0 + (c & 3) * 8,
                       Bs + (j * 4 + w) * 512);
        }
        __syncthreads();
        short8 af[4], bfr[4];
        #pragma unroll
        for (int mi = 0; mi < 4; ++mi)
            af[mi] = *(const short8*)&As[(wm * 64 + mi * 16 + lq) * 32 + lg * 8];
        #pragma unroll
        for (int ni = 0; ni < 4; ++ni)
            bfr[ni] = *(const short8*)&Bs[(wn * 64 + ni * 16 + lq) * 32 + lg * 8];
        #pragma unroll
        for (int mi = 0; mi < 4; ++mi)
            #pragma unroll
            for (int ni = 0; ni < 4; ++ni)
                acc[mi][ni] = __builtin_amdgcn_mfma_f32_16x16x32_bf16(
                    af[mi], bfr[ni], acc[mi][ni], 0, 0, 0);
    }

    // epilogue: direct fp32 stores from C-fragment layout
    const int mrow0 = m0 + wm * 64;
    const int ncol0 = n0 + wn * 64;
    float bias4[4];
    #pragma unroll
    for (int ni = 0; ni < 4; ++ni)
        bias4[ni] = bias[ncol0 + ni * 16 + lq];

    #pragma unroll
    for (int mi = 0; mi < 4; ++mi)
        #pragma unroll
        for (int r = 0; r < 4; ++r) {
            const size_t rowoff = (size_t)(mrow0 + mi * 16 + lg * 4 + r) * 1024;
            #pragma unroll
            for (int ni = 0; ni < 4; ++ni)
                out[rowoff + ncol0 + ni * 16 + lq] = acc[mi][ni][r] + bias4[ni];
        }
}

// ======================= launcher =======================

extern "C" void kernel_launch(void* const* d_in, const int* in_sizes, int n_in,
                              void* d_out, int out_size, void* d_ws, size_t ws_size,
                              hipStream_t stream) {
    const float* x    = (const float*)d_in[0];
    // d_in[1] (causal mask) applied structurally.
    const float* Wqkv = (const float*)d_in[2];
    const float* bqkv = (const float*)d_in[3];
    const float* Wo   = (const float*)d_in[4];
    const float* bo   = (const float*)d_in[5];

    const size_t QK = (size_t)BB * HH * NN * SS;  // 4,194,304

    uint16_t* Xb  = (uint16_t*)d_ws;
    uint16_t* Wqb = Xb + XE;
    uint16_t* Wob = Wqb + WQE;
    uint16_t* Qb  = Wob + WOE;
    uint16_t* Kb  = Qb + QK;
    uint16_t* Vt  = Kb + QK;
    uint16_t* Yb  = Vt + QK;

    cvt_all<<<(XE + WQE + WOE) / 8 / 256, 256, 0, stream>>>(x, Wqkv, Wo, Xb);
    gemm_qkv<<<dim3(24, 32), 256, 0, stream>>>(Xb, Wqb, bqkv, Qb, Kb, Vt);
    attn_mfma<<<2048, 128, 0, stream>>>(Qb, Kb, Vt, Yb);
    gemm_proj<<<dim3(8, 32), 256, 0, stream>>>(Yb, Wob, bo, (float*)d_out);
}

// Round 15
// 141.423 us; speedup vs baseline: 1.7513x; 1.0601x over previous
//
#include <hip/hip_runtime.h>
#include <hip/hip_bf16.h>
#include <stdint.h>

// Problem constants: B=2, N=2048, D=1024, H=16, head dim s=64.
// Global I/O fp32; internal X/W/Q/K/V/Y intermediates bf16 in d_ws.
// Q is pre-scaled by 0.125*log2e so attention softmax runs in exp2 domain.
#define BB 2
#define NN 2048
#define DD 1024
#define HH 16
#define SS 64

typedef short short8 __attribute__((ext_vector_type(8)));
typedef float f32x4 __attribute__((ext_vector_type(4)));

__device__ __forceinline__ float bf2f(uint16_t u) {
    return __uint_as_float(((uint32_t)u) << 16);
}
__device__ __forceinline__ uint16_t f2bf(float f) {
    uint32_t u = __float_as_uint(f);
    return (uint16_t)((u + 0x7FFFu + ((u >> 16) & 1u)) >> 16);  // RNE
}
__device__ __forceinline__ short8 cvt8(float4 a, float4 b) {
    short8 s;
    s[0] = (short)f2bf(a.x); s[1] = (short)f2bf(a.y);
    s[2] = (short)f2bf(a.z); s[3] = (short)f2bf(a.w);
    s[4] = (short)f2bf(b.x); s[5] = (short)f2bf(b.y);
    s[6] = (short)f2bf(b.z); s[7] = (short)f2bf(b.w);
    return s;
}

__device__ __forceinline__ void load_lds16(const uint16_t* g, uint16_t* l) {
    __builtin_amdgcn_global_load_lds(
        (const __attribute__((address_space(1))) void*)g,
        (__attribute__((address_space(3))) void*)l, 16, 0, 0);
}

#define XE  (4096 * 1024)
#define WQE (3072 * 1024)
#define WOE (1024 * 1024)

// ======================= fused fp32 -> bf16 bulk convert =======================
__global__ __launch_bounds__(256) void cvt_all(
    const float* __restrict__ x, const float* __restrict__ wq,
    const float* __restrict__ wo, uint16_t* __restrict__ dst)
{
    int i = (blockIdx.x * 256 + threadIdx.x) * 8;
    const float* src;
    int off;
    if (i < XE)            { src = x;  off = i; }
    else if (i < XE + WQE) { src = wq; off = i - XE; }
    else                   { src = wo; off = i - XE - WQE; }
    float4 a = *(const float4*)(src + off);
    float4 b = *(const float4*)(src + off + 4);
    *(short8*)(dst + i) = cvt8(a, b);
}

// ======================= QKV projection (MFMA, bf16 in) =======================
// C[4096,3072] = X[4096,1024] @ Wqkv[3072,1024]^T + bqkv
// -> Q bf16 (x0.125*log2e) [bh][2048][64], K bf16 [bh][2048][64], V^T [bh][64][2048]
// BK=64 (two [128][32] half-tiles per barrier pair -> 32 MFMA/barrier, half the
// barrier drains of BK=32). XCD swizzle: each XCD owns a 3-col B strip (768KB,
// L2-resident) x all M; A panels reused 3x back-to-back.
__global__ __launch_bounds__(256) void gemm_qkv(
    const uint16_t* __restrict__ X, const uint16_t* __restrict__ W,
    const float* __restrict__ bias,
    uint16_t* __restrict__ Qb, uint16_t* __restrict__ Kb, uint16_t* __restrict__ Vt)
{
    __shared__ __align__(16) uint16_t smem[18432];   // 36,864 B
    uint16_t* As0 = smem;            // [128][32]
    uint16_t* As1 = smem + 4096;
    uint16_t* Bs0 = smem + 8192;
    uint16_t* Bs1 = smem + 12288;

    const int tid = threadIdx.x;
    const int w = tid >> 6, l = tid & 63;
    const int lq = l & 15, lg = l >> 4;
    const int wm = w >> 1, wn = w & 1;

    // XCD-aware remap (768 blocks, 768%8==0 -> bijective):
    // xcd owns x in [xcd*3, xcd*3+3), y walks 0..31; x varies fastest (A reuse 3x).
    const int flat = blockIdx.x + blockIdx.y * 24;
    const int xcd = flat & 7, g = flat >> 3;
    const int n0 = (xcd * 3 + (g % 3)) * 128;
    const int m0 = (g / 3) * 128;

    f32x4 acc[4][4] = {};

    for (int k0 = 0; k0 < 1024; k0 += 64) {
        __syncthreads();
        #pragma unroll
        for (int j = 0; j < 2; ++j) {
            const int c = (j * 4 + w) * 64 + l;   // lane's global row/col chunk
            const size_t ra = (size_t)(m0 + (c >> 2)) * 1024 + k0 + (c & 3) * 8;
            const size_t rb = (size_t)(n0 + (c >> 2)) * 1024 + k0 + (c & 3) * 8;
            load_lds16(X + ra,      As0 + (j * 4 + w) * 512);
            load_lds16(X + ra + 32, As1 + (j * 4 + w) * 512);
            load_lds16(W + rb,      Bs0 + (j * 4 + w) * 512);
            load_lds16(W + rb + 32, Bs1 + (j * 4 + w) * 512);
        }
        __syncthreads();
        short8 af[4], bfr[4];
        #pragma unroll
        for (int mi = 0; mi < 4; ++mi)
            af[mi] = *(const short8*)&As0[(wm * 64 + mi * 16 + lq) * 32 + lg * 8];
        #pragma unroll
        for (int ni = 0; ni < 4; ++ni)
            bfr[ni] = *(const short8*)&Bs0[(wn * 64 + ni * 16 + lq) * 32 + lg * 8];
        #pragma unroll
        for (int mi = 0; mi < 4; ++mi)
            #pragma unroll
            for (int ni = 0; ni < 4; ++ni)
                acc[mi][ni] = __builtin_amdgcn_mfma_f32_16x16x32_bf16(
                    af[mi], bfr[ni], acc[mi][ni], 0, 0, 0);
        #pragma unroll
        for (int mi = 0; mi < 4; ++mi)
            af[mi] = *(const short8*)&As1[(wm * 64 + mi * 16 + lq) * 32 + lg * 8];
        #pragma unroll
        for (int ni = 0; ni < 4; ++ni)
            bfr[ni] = *(const short8*)&Bs1[(wn * 64 + ni * 16 + lq) * 32 + lg * 8];
        #pragma unroll
        for (int mi = 0; mi < 4; ++mi)
            #pragma unroll
            for (int ni = 0; ni < 4; ++ni)
                acc[mi][ni] = __builtin_amdgcn_mfma_f32_16x16x32_bf16(
                    af[mi], bfr[ni], acc[mi][ni], 0, 0, 0);
    }

    // ---------------- epilogue: bf16 scatter via LDS transpose ----------------
    __syncthreads();  // staging reads complete; reuse smem
    const int part = n0 >> 10;                       // 0=Q 1=K 2=V (uniform)
    const int hh = ((n0 + wn * 64) & 1023) >> 6;     // head (uniform per wave)
    const int mrow0 = m0 + wm * 64;
    const int bh = (mrow0 >> 11) * 16 + hh;
    const int tok0 = mrow0 & 2047;
    // Q pre-scale folds 1/sqrt(64) and log2e for exp2-domain softmax.
    const float scl = (part == 0) ? 0.125f * 1.44269504089f : 1.0f;

    float bias4[4];
    #pragma unroll
    for (int ni = 0; ni < 4; ++ni)
        bias4[ni] = bias[n0 + wn * 64 + ni * 16 + lq];

    uint16_t* T = smem + w * 4608;                   // [64][72] bf16, wave-private
    if (part < 2) {
        #pragma unroll
        for (int mi = 0; mi < 4; ++mi)
            #pragma unroll
            for (int ni = 0; ni < 4; ++ni)
                #pragma unroll
                for (int r = 0; r < 4; ++r)
                    T[(mi * 16 + lg * 4 + r) * 72 + ni * 16 + lq] =
                        f2bf((acc[mi][ni][r] + bias4[ni]) * scl);
    } else {
        #pragma unroll
        for (int mi = 0; mi < 4; ++mi)
            #pragma unroll
            for (int ni = 0; ni < 4; ++ni)
                #pragma unroll
                for (int r = 0; r < 4; ++r)
                    T[(ni * 16 + lq) * 72 + mi * 16 + lg * 4 + r] =
                        f2bf(acc[mi][ni][r] + bias4[ni]);
    }

    const int a0 = l >> 3, b8 = (l & 7) * 8;
    #pragma unroll
    for (int i = 0; i < 8; ++i) {
        int a = i * 8 + a0;
        short8 u = *(short8*)&T[a * 72 + b8];
        uint16_t* p;
        if (part < 2) {
            uint16_t* dst = (part == 0) ? Qb : Kb;
            p = dst + ((size_t)bh * 2048 + tok0 + a) * 64 + b8;
        } else {
            p = Vt + ((size_t)bh * 64 + a) * 2048 + tok0 + b8;
        }
        *(short8*)p = u;
    }
}

// ======================= MFMA flash attention (kv-split, 2 waves/block) =========
// (unchanged from round 14: 2048 blocks x 128 thr, swapped QK^T, exp2/defer,
//  per-lane lsum, exact in-LDS merge.)
__device__ __forceinline__ void loadKf(const uint16_t* Kb, int kv0, int lq, int lg,
                                       short8 (&d)[8]) {
    #pragma unroll
    for (int n = 0; n < 4; ++n) {
        const uint16_t* kb = Kb + (size_t)(kv0 + n * 16 + lq) * 64 + lg * 8;
        d[2 * n]     = *(const short8*)kb;
        d[2 * n + 1] = *(const short8*)(kb + 32);
    }
}
__device__ __forceinline__ void loadVf(const uint16_t* Vb, int kv0, int lq, int lg,
                                       short8 (&d)[8]) {
    #pragma unroll
    for (int n = 0; n < 4; ++n) {
        const uint16_t* vb = Vb + (size_t)(n * 16 + lq) * 2048 + kv0 + lg * 8;
        d[2 * n]     = *(const short8*)vb;
        d[2 * n + 1] = *(const short8*)(vb + 32);
    }
}

#define DEFER_THR 11.5f   // ~8 nats in log2 units

__global__ __launch_bounds__(128) void attn_mfma(
    const uint16_t* __restrict__ Q, const uint16_t* __restrict__ K,
    const uint16_t* __restrict__ Vt, uint16_t* __restrict__ Y)
{
    const int id = blockIdx.x;
    const int bh = id & 31;               // id%8 -> stable XCD per bh group
    const int blk = 63 - (id >> 5);       // 32-row q-block, heaviest first
    const int qt = blk >> 1;              // last kv tile index
    const int q0 = blk * 32;

    const int wv = threadIdx.x >> 6;      // 0 or 1: kv-parity this wave owns
    const int lane = threadIdx.x & 63;
    const int lq = lane & 15;
    const int lg = lane >> 4;

    __shared__ __align__(16) uint16_t Pl[2][2][16][72];  // [wave][sub]
    __shared__ float  My[32][68];                        // wave1 partial y (padded)
    __shared__ float2 Mml[32];                           // wave1 (m, lsum) per q-row

    const uint16_t* Kb = K + (size_t)bh * (2048 * 64);
    const uint16_t* Vb = Vt + (size_t)bh * (64 * 2048);
    const int b = bh >> 4, h = bh & 15;

    short8 qf[2][2];
    #pragma unroll
    for (int sub = 0; sub < 2; ++sub) {
        const uint16_t* qb = Q + ((size_t)bh * 2048 + q0 + sub * 16 + lq) * 64 + lg * 8;
        qf[sub][0] = *(const short8*)qb;
        qf[sub][1] = *(const short8*)(qb + 32);
    }

    f32x4 y[2][4] = {};
    float m[2]    = {-INFINITY, -INFINITY};   // scalar state: lane's q = q0s + lq
    float lsum[2] = {0.f, 0.f};               // per-lane partial

    short8 kf[8], vv[8];
    loadKf(Kb, wv * 64, lq, lg, kf);          // first owned tile (always in-bounds)

    for (int kt = wv; kt <= qt; kt += 2) {
        const int kv0 = kt * 64;
        loadVf(Vb, kv0, lq, lg, vv);

        // ---- swapped QK^T: z[sub][n][r] = S[q0s+lq][kv0 + n*16 + lg*4 + r] ----
        f32x4 z[2][4];
        __builtin_amdgcn_s_setprio(1);
        #pragma unroll
        for (int sub = 0; sub < 2; ++sub)
            #pragma unroll
            for (int n = 0; n < 4; ++n) {
                f32x4 t = {};
                t = __builtin_amdgcn_mfma_f32_16x16x32_bf16(kf[2 * n], qf[sub][0], t, 0, 0, 0);
                z[sub][n] = __builtin_amdgcn_mfma_f32_16x16x32_bf16(kf[2 * n + 1], qf[sub][1], t, 0, 0, 0);
            }
        __builtin_amdgcn_s_setprio(0);

        // refill K for this wave's next tile (kt+2)
        if (kt + 2 <= qt) loadKf(Kb, kv0 + 128, lq, lg, kf);

        #pragma unroll
        for (int sub = 0; sub < 2; ++sub) {
            if (kt == qt) {
                const int qrow = q0 + sub * 16 + lq;
                #pragma unroll
                for (int n = 0; n < 4; ++n) {
                    const int kvb = kv0 + n * 16 + lg * 4;
                    #pragma unroll
                    for (int r = 0; r < 4; ++r)
                        if (kvb + r > qrow) z[sub][n][r] = -INFINITY;
                }
            }
            // ---- per-lane partial max + one ballot ----
            float mt = -INFINITY;
            #pragma unroll
            for (int n = 0; n < 4; ++n)
                #pragma unroll
                for (int r = 0; r < 4; ++r)
                    mt = fmaxf(mt, z[sub][n][r]);
            const bool skip = __all(mt - m[sub] <= DEFER_THR);

            if (!skip) {   // rare: reduce across the 4 lg-groups (same q = lq)
                float mf = fmaxf(mt, __shfl_xor(mt, 16));
                mf = fmaxf(mf, __shfl_xor(mf, 32));
                const float mn = fmaxf(m[sub], mf);
                const float sc = exp2f(m[sub] - mn);
                m[sub] = mn;
                lsum[sub] *= sc;
                float scy[4];
                #pragma unroll
                for (int r = 0; r < 4; ++r) scy[r] = __shfl(sc, lg * 4 + r);
                #pragma unroll
                for (int n = 0; n < 4; ++n)
                    #pragma unroll
                    for (int r = 0; r < 4; ++r)
                        y[sub][n][r] *= scy[r];
            }

            // ---- exp2, pack pairs via cvt_pk, 4x ds_write_b64 ----
            float ps = 0.f;
            uint32_t pk0[4], pk1[4];
            #pragma unroll
            for (int n = 0; n < 4; ++n) {
                float e0 = exp2f(z[sub][n][0] - m[sub]);
                float e1 = exp2f(z[sub][n][1] - m[sub]);
                float e2 = exp2f(z[sub][n][2] - m[sub]);
                float e3 = exp2f(z[sub][n][3] - m[sub]);
                ps += (e0 + e1) + (e2 + e3);
                asm("v_cvt_pk_bf16_f32 %0, %1, %2" : "=v"(pk0[n]) : "v"(e0), "v"(e1));
                asm("v_cvt_pk_bf16_f32 %0, %1, %2" : "=v"(pk1[n]) : "v"(e2), "v"(e3));
            }
            lsum[sub] += ps;
            #pragma unroll
            for (int n = 0; n < 4; ++n) {
                uint2 u; u.x = pk0[n]; u.y = pk1[n];
                *(uint2*)&Pl[wv][sub][lq][n * 16 + lg * 4] = u;
            }

            short8 pa0 = *(short8*)&Pl[wv][sub][lq][lg * 8];
            short8 pa1 = *(short8*)&Pl[wv][sub][lq][lg * 8 + 32];
            __builtin_amdgcn_s_setprio(1);
            #pragma unroll
            for (int n = 0; n < 4; ++n) {
                y[sub][n] = __builtin_amdgcn_mfma_f32_16x16x32_bf16(pa0, vv[2 * n], y[sub][n], 0, 0, 0);
                y[sub][n] = __builtin_amdgcn_mfma_f32_16x16x32_bf16(pa1, vv[2 * n + 1], y[sub][n], 0, 0, 0);
            }
            __builtin_amdgcn_s_setprio(0);
        }
    }

    // ---- reduce per-lane lsum across lg groups (both waves) ----
    float ls[2];
    #pragma unroll
    for (int sub = 0; sub < 2; ++sub) {
        float t = lsum[sub];
        t += __shfl_xor(t, 16);
        t += __shfl_xor(t, 32);
        ls[sub] = t;
    }

    // ---- merge: wave1 posts partials; wave0 combines + writes ----
    if (wv == 1) {
        #pragma unroll
        for (int sub = 0; sub < 2; ++sub) {
            #pragma unroll
            for (int n = 0; n < 4; ++n)
                #pragma unroll
                for (int r = 0; r < 4; ++r)
                    My[sub * 16 + lg * 4 + r][n * 16 + lq] = y[sub][n][r];
            if (lg == 0) Mml[sub * 16 + lq] = make_float2(m[sub], ls[sub]);
        }
    }
    __syncthreads();
    if (wv == 0) {
        #pragma unroll
        for (int sub = 0; sub < 2; ++sub) {
            float2 o = Mml[sub * 16 + lq];
            const float m1 = o.x, l1 = o.y;
            const float mx = fmaxf(m[sub], m1);
            const float w0 = exp2f(m[sub] - mx);
            const float w1 = exp2f(m1 - mx);
            const float inv = 1.0f / (ls[sub] * w0 + l1 * w1);
            const float f0 = w0 * inv, f1 = w1 * inv;
            float f0r[4], f1r[4];
            #pragma unroll
            for (int r = 0; r < 4; ++r) {
                f0r[r] = __shfl(f0, lg * 4 + r);
                f1r[r] = __shfl(f1, lg * 4 + r);
            }
            #pragma unroll
            for (int r = 0; r < 4; ++r) {
                int token = b * 2048 + q0 + sub * 16 + lg * 4 + r;
                uint16_t* yrow = Y + (size_t)token * 1024 + h * 64;
                #pragma unroll
                for (int n = 0; n < 4; ++n) {
                    float val = y[sub][n][r] * f0r[r] +
                                My[sub * 16 + lg * 4 + r][n * 16 + lq] * f1r[r];
                    yrow[n * 16 + lq] = f2bf(val);
                }
            }
        }
    }
}

// ======================= output projection (MFMA, fp32 out) =======================
// out[4096,1024] = Y(bf16) @ Wo(bf16)^T + bo. BK=64 + XCD swizzle (1 col/XCD).
__global__ __launch_bounds__(256) void gemm_proj(
    const uint16_t* __restrict__ Yin, const uint16_t* __restrict__ W,
    const float* __restrict__ bias, float* __restrict__ out)
{
    __shared__ __align__(16) uint16_t smem[16384];   // 4 x [128][32] = 32 KB
    uint16_t* As0 = smem;
    uint16_t* As1 = smem + 4096;
    uint16_t* Bs0 = smem + 8192;
    uint16_t* Bs1 = smem + 12288;

    const int tid = threadIdx.x;
    const int w = tid >> 6, l = tid & 63;
    const int lq = l & 15, lg = l >> 4;
    const int wm = w >> 1, wn = w & 1;

    // XCD remap: 256 blocks, xcd owns one x-col (B panel L2-resident), y walks.
    const int flat = blockIdx.x + blockIdx.y * 8;
    const int n0 = (flat & 7) * 128;
    const int m0 = (flat >> 3) * 128;

    f32x4 acc[4][4] = {};

    for (int k0 = 0; k0 < 1024; k0 += 64) {
        __syncthreads();
        #pragma unroll
        for (int j = 0; j < 2; ++j) {
            const int c = (j * 4 + w) * 64 + l;
            const size_t ra = (size_t)(m0 + (c >> 2)) * 1024 + k0 + (c & 3) * 8;
            const size_t rb = (size_t)(n0 + (c >> 2)) * 1024 + k0 + (c & 3) * 8;
            load_lds16(Yin + ra,      As0 + (j * 4 + w) * 512);
            load_lds16(Yin + ra + 32, As1 + (j * 4 + w) * 512);
            load_lds16(W + rb,        Bs0 + (j * 4 + w) * 512);
            load_lds16(W + rb + 32,   Bs1 + (j * 4 + w) * 512);
        }
        __syncthreads();
        short8 af[4], bfr[4];
        #pragma unroll
        for (int mi = 0; mi < 4; ++mi)
            af[mi] = *(const short8*)&As0[(wm * 64 + mi * 16 + lq) * 32 + lg * 8];
        #pragma unroll
        for (int ni = 0; ni < 4; ++ni)
            bfr[ni] = *(const short8*)&Bs0[(wn * 64 + ni * 16 + lq) * 32 + lg * 8];
        #pragma unroll
        for (int mi = 0; mi < 4; ++mi)
            #pragma unroll
            for (int ni = 0; ni < 4; ++ni)
                acc[mi][ni] = __builtin_amdgcn_mfma_f32_16x16x32_bf16(
                    af[mi], bfr[ni], acc[mi][ni], 0, 0, 0);
        #pragma unroll
        for (int mi = 0; mi < 4; ++mi)
            af[mi] = *(const short8*)&As1[(wm * 64 + mi * 16 + lq) * 32 + lg * 8];
        #pragma unroll
        for (int ni = 0; ni < 4; ++ni)
            bfr[ni] = *(const short8*)&Bs1[(wn * 64 + ni * 16 + lq) * 32 + lg * 8];
        #pragma unroll
        for (int mi = 0; mi < 4; ++mi)
            #pragma unroll
            for (int ni = 0; ni < 4; ++ni)
                acc[mi][ni] = __builtin_amdgcn_mfma_f32_16x16x32_bf16(
                    af[mi], bfr[ni], acc[mi][ni], 0, 0, 0);
    }

    // epilogue: direct fp32 stores from C-fragment layout
    const int mrow0 = m0 + wm * 64;
    const int ncol0 = n0 + wn * 64;
    float bias4[4];
    #pragma unroll
    for (int ni = 0; ni < 4; ++ni)
        bias4[ni] = bias[ncol0 + ni * 16 + lq];

    #pragma unroll
    for (int mi = 0; mi < 4; ++mi)
        #pragma unroll
        for (int r = 0; r < 4; ++r) {
            const size_t rowoff = (size_t)(mrow0 + mi * 16 + lg * 4 + r) * 1024;
            #pragma unroll
            for (int ni = 0; ni < 4; ++ni)
                out[rowoff + ncol0 + ni * 16 + lq] = acc[mi][ni][r] + bias4[ni];
        }
}

// ======================= launcher =======================

extern "C" void kernel_launch(void* const* d_in, const int* in_sizes, int n_in,
                              void* d_out, int out_size, void* d_ws, size_t ws_size,
                              hipStream_t stream) {
    const float* x    = (const float*)d_in[0];
    // d_in[1] (causal mask) applied structurally.
    const float* Wqkv = (const float*)d_in[2];
    const float* bqkv = (const float*)d_in[3];
    const float* Wo   = (const float*)d_in[4];
    const float* bo   = (const float*)d_in[5];

    const size_t QK = (size_t)BB * HH * NN * SS;  // 4,194,304

    uint16_t* Xb  = (uint16_t*)d_ws;
    uint16_t* Wqb = Xb + XE;
    uint16_t* Wob = Wqb + WQE;
    uint16_t* Qb  = Wob + WOE;
    uint16_t* Kb  = Qb + QK;
    uint16_t* Vt  = Kb + QK;
    uint16_t* Yb  = Vt + QK;

    cvt_all<<<(XE + WQE + WOE) / 8 / 256, 256, 0, stream>>>(x, Wqkv, Wo, Xb);
    gemm_qkv<<<dim3(24, 32), 256, 0, stream>>>(Xb, Wqb, bqkv, Qb, Kb, Vt);
    attn_mfma<<<2048, 128, 0, stream>>>(Qb, Kb, Vt, Yb);
    gemm_proj<<<dim3(8, 32), 256, 0, stream>>>(Yb, Wob, bo, (float*)d_out);
}

// Round 16
// 139.554 us; speedup vs baseline: 1.7748x; 1.0134x over previous
//
#include <hip/hip_runtime.h>
#include <hip/hip_bf16.h>
#include <stdint.h>

// Problem constants: B=2, N=2048, D=1024, H=16, head dim s=64.
// Global I/O fp32; internal X/W/Q/K/V/Y intermediates bf16 in d_ws.
// Q is pre-scaled by 0.125*log2e so attention softmax runs in exp2 domain.
#define BB 2
#define NN 2048
#define DD 1024
#define HH 16
#define SS 64

typedef short short8 __attribute__((ext_vector_type(8)));
typedef float f32x4 __attribute__((ext_vector_type(4)));

__device__ __forceinline__ float bf2f(uint16_t u) {
    return __uint_as_float(((uint32_t)u) << 16);
}
__device__ __forceinline__ uint16_t f2bf(float f) {
    uint32_t u = __float_as_uint(f);
    return (uint16_t)((u + 0x7FFFu + ((u >> 16) & 1u)) >> 16);  // RNE
}
__device__ __forceinline__ short8 cvt8(float4 a, float4 b) {
    short8 s;
    s[0] = (short)f2bf(a.x); s[1] = (short)f2bf(a.y);
    s[2] = (short)f2bf(a.z); s[3] = (short)f2bf(a.w);
    s[4] = (short)f2bf(b.x); s[5] = (short)f2bf(b.y);
    s[6] = (short)f2bf(b.z); s[7] = (short)f2bf(b.w);
    return s;
}

__device__ __forceinline__ void load_lds16(const uint16_t* g, uint16_t* l) {
    __builtin_amdgcn_global_load_lds(
        (const __attribute__((address_space(1))) void*)g,
        (__attribute__((address_space(3))) void*)l, 16, 0, 0);
}

#define XE  (4096 * 1024)
#define WQE (3072 * 1024)
#define WOE (1024 * 1024)

// ======================= fused fp32 -> bf16 bulk convert =======================
__global__ __launch_bounds__(256) void cvt_all(
    const float* __restrict__ x, const float* __restrict__ wq,
    const float* __restrict__ wo, uint16_t* __restrict__ dst)
{
    int i = (blockIdx.x * 256 + threadIdx.x) * 8;
    const float* src;
    int off;
    if (i < XE)            { src = x;  off = i; }
    else if (i < XE + WQE) { src = wq; off = i - XE; }
    else                   { src = wo; off = i - XE - WQE; }
    float4 a = *(const float4*)(src + off);
    float4 b = *(const float4*)(src + off + 4);
    *(short8*)(dst + i) = cvt8(a, b);
}

// ======================= QKV projection (MFMA, bf16 in) =======================
// C[4096,3072] = X[4096,1024] @ Wqkv[3072,1024]^T + bqkv
// -> Q bf16 (x0.125*log2e) [bh][2048][64], K bf16 [bh][2048][64], V^T [bh][64][2048]
// BK=64 + XCD swizzle (unchanged from round 15).
__global__ __launch_bounds__(256) void gemm_qkv(
    const uint16_t* __restrict__ X, const uint16_t* __restrict__ W,
    const float* __restrict__ bias,
    uint16_t* __restrict__ Qb, uint16_t* __restrict__ Kb, uint16_t* __restrict__ Vt)
{
    __shared__ __align__(16) uint16_t smem[18432];   // 36,864 B
    uint16_t* As0 = smem;            // [128][32]
    uint16_t* As1 = smem + 4096;
    uint16_t* Bs0 = smem + 8192;
    uint16_t* Bs1 = smem + 12288;

    const int tid = threadIdx.x;
    const int w = tid >> 6, l = tid & 63;
    const int lq = l & 15, lg = l >> 4;
    const int wm = w >> 1, wn = w & 1;

    const int flat = blockIdx.x + blockIdx.y * 24;
    const int xcd = flat & 7, g = flat >> 3;
    const int n0 = (xcd * 3 + (g % 3)) * 128;
    const int m0 = (g / 3) * 128;

    f32x4 acc[4][4] = {};

    for (int k0 = 0; k0 < 1024; k0 += 64) {
        __syncthreads();
        #pragma unroll
        for (int j = 0; j < 2; ++j) {
            const int c = (j * 4 + w) * 64 + l;
            const size_t ra = (size_t)(m0 + (c >> 2)) * 1024 + k0 + (c & 3) * 8;
            const size_t rb = (size_t)(n0 + (c >> 2)) * 1024 + k0 + (c & 3) * 8;
            load_lds16(X + ra,      As0 + (j * 4 + w) * 512);
            load_lds16(X + ra + 32, As1 + (j * 4 + w) * 512);
            load_lds16(W + rb,      Bs0 + (j * 4 + w) * 512);
            load_lds16(W + rb + 32, Bs1 + (j * 4 + w) * 512);
        }
        __syncthreads();
        short8 af[4], bfr[4];
        #pragma unroll
        for (int mi = 0; mi < 4; ++mi)
            af[mi] = *(const short8*)&As0[(wm * 64 + mi * 16 + lq) * 32 + lg * 8];
        #pragma unroll
        for (int ni = 0; ni < 4; ++ni)
            bfr[ni] = *(const short8*)&Bs0[(wn * 64 + ni * 16 + lq) * 32 + lg * 8];
        #pragma unroll
        for (int mi = 0; mi < 4; ++mi)
            #pragma unroll
            for (int ni = 0; ni < 4; ++ni)
                acc[mi][ni] = __builtin_amdgcn_mfma_f32_16x16x32_bf16(
                    af[mi], bfr[ni], acc[mi][ni], 0, 0, 0);
        #pragma unroll
        for (int mi = 0; mi < 4; ++mi)
            af[mi] = *(const short8*)&As1[(wm * 64 + mi * 16 + lq) * 32 + lg * 8];
        #pragma unroll
        for (int ni = 0; ni < 4; ++ni)
            bfr[ni] = *(const short8*)&Bs1[(wn * 64 + ni * 16 + lq) * 32 + lg * 8];
        #pragma unroll
        for (int mi = 0; mi < 4; ++mi)
            #pragma unroll
            for (int ni = 0; ni < 4; ++ni)
                acc[mi][ni] = __builtin_amdgcn_mfma_f32_16x16x32_bf16(
                    af[mi], bfr[ni], acc[mi][ni], 0, 0, 0);
    }

    // ---------------- epilogue: bf16 scatter via LDS transpose ----------------
    __syncthreads();
    const int part = n0 >> 10;
    const int hh = ((n0 + wn * 64) & 1023) >> 6;
    const int mrow0 = m0 + wm * 64;
    const int bh = (mrow0 >> 11) * 16 + hh;
    const int tok0 = mrow0 & 2047;
    const float scl = (part == 0) ? 0.125f * 1.44269504089f : 1.0f;

    float bias4[4];
    #pragma unroll
    for (int ni = 0; ni < 4; ++ni)
        bias4[ni] = bias[n0 + wn * 64 + ni * 16 + lq];

    uint16_t* T = smem + w * 4608;                   // [64][72] bf16, wave-private
    if (part < 2) {
        #pragma unroll
        for (int mi = 0; mi < 4; ++mi)
            #pragma unroll
            for (int ni = 0; ni < 4; ++ni)
                #pragma unroll
                for (int r = 0; r < 4; ++r)
                    T[(mi * 16 + lg * 4 + r) * 72 + ni * 16 + lq] =
                        f2bf((acc[mi][ni][r] + bias4[ni]) * scl);
    } else {
        #pragma unroll
        for (int mi = 0; mi < 4; ++mi)
            #pragma unroll
            for (int ni = 0; ni < 4; ++ni)
                #pragma unroll
                for (int r = 0; r < 4; ++r)
                    T[(ni * 16 + lq) * 72 + mi * 16 + lg * 4 + r] =
                        f2bf(acc[mi][ni][r] + bias4[ni]);
    }

    const int a0 = l >> 3, b8 = (l & 7) * 8;
    #pragma unroll
    for (int i = 0; i < 8; ++i) {
        int a = i * 8 + a0;
        short8 u = *(short8*)&T[a * 72 + b8];
        uint16_t* p;
        if (part < 2) {
            uint16_t* dst = (part == 0) ? Qb : Kb;
            p = dst + ((size_t)bh * 2048 + tok0 + a) * 64 + b8;
        } else {
            p = Vt + ((size_t)bh * 64 + a) * 2048 + tok0 + b8;
        }
        *(short8*)p = u;
    }
}

// ======================= MFMA flash attention (kv-split, interleaved subs) ======
// 2048 blocks x 128 thr. r16 changes: (1) both substrips' exp+pack+LDS-writes
// issued before any P-read (sub1 math hides sub0 write latency; one wait region
// per step), (2) single combined defer ballot, (3) masked/final tile peeled out
// of the steady-state loop (no mask branch, unconditional K prefetch).
__device__ __forceinline__ void loadKf(const uint16_t* Kb, int kv0, int lq, int lg,
                                       short8 (&d)[8]) {
    #pragma unroll
    for (int n = 0; n < 4; ++n) {
        const uint16_t* kb = Kb + (size_t)(kv0 + n * 16 + lq) * 64 + lg * 8;
        d[2 * n]     = *(const short8*)kb;
        d[2 * n + 1] = *(const short8*)(kb + 32);
    }
}
__device__ __forceinline__ void loadVf(const uint16_t* Vb, int kv0, int lq, int lg,
                                       short8 (&d)[8]) {
    #pragma unroll
    for (int n = 0; n < 4; ++n) {
        const uint16_t* vb = Vb + (size_t)(n * 16 + lq) * 2048 + kv0 + lg * 8;
        d[2 * n]     = *(const short8*)vb;
        d[2 * n + 1] = *(const short8*)(vb + 32);
    }
}

#define DEFER_THR 11.5f   // ~8 nats in log2 units

__global__ __launch_bounds__(128) void attn_mfma(
    const uint16_t* __restrict__ Q, const uint16_t* __restrict__ K,
    const uint16_t* __restrict__ Vt, uint16_t* __restrict__ Y)
{
    const int id = blockIdx.x;
    const int bh = id & 31;               // id%8 -> stable XCD per bh group
    const int blk = 63 - (id >> 5);       // 32-row q-block, heaviest first
    const int qt = blk >> 1;              // last kv tile index
    const int q0 = blk * 32;

    const int wv = threadIdx.x >> 6;      // 0 or 1: kv-parity this wave owns
    const int lane = threadIdx.x & 63;
    const int lq = lane & 15;
    const int lg = lane >> 4;

    __shared__ __align__(16) uint16_t Pl[2][2][16][72];  // [wave][sub]
    __shared__ float  My[32][68];                        // wave1 partial y (padded)
    __shared__ float2 Mml[32];                           // wave1 (m, lsum) per q-row

    const uint16_t* Kb = K + (size_t)bh * (2048 * 64);
    const uint16_t* Vb = Vt + (size_t)bh * (64 * 2048);
    const int b = bh >> 4, h = bh & 15;

    short8 qf[2][2];
    #pragma unroll
    for (int sub = 0; sub < 2; ++sub) {
        const uint16_t* qb = Q + ((size_t)bh * 2048 + q0 + sub * 16 + lq) * 64 + lg * 8;
        qf[sub][0] = *(const short8*)qb;
        qf[sub][1] = *(const short8*)(qb + 32);
    }

    f32x4 y[2][4] = {};
    float m[2]    = {-INFINITY, -INFINITY};   // scalar state: lane's q = q0s + lq
    float lsum[2] = {0.f, 0.f};               // per-lane partial

    short8 kf[8], vv[8];
    loadKf(Kb, wv * 64, lq, lg, kf);          // first owned tile

    auto step = [&](int kv0, bool domask, bool pref) {
        loadVf(Vb, kv0, lq, lg, vv);

        // ---- swapped QK^T: z[sub][n][r] = S[q0s+lq][kv0 + n*16 + lg*4 + r] ----
        f32x4 z[2][4];
        __builtin_amdgcn_s_setprio(1);
        #pragma unroll
        for (int sub = 0; sub < 2; ++sub)
            #pragma unroll
            for (int n = 0; n < 4; ++n) {
                f32x4 t = {};
                t = __builtin_amdgcn_mfma_f32_16x16x32_bf16(kf[2 * n], qf[sub][0], t, 0, 0, 0);
                z[sub][n] = __builtin_amdgcn_mfma_f32_16x16x32_bf16(kf[2 * n + 1], qf[sub][1], t, 0, 0, 0);
            }
        __builtin_amdgcn_s_setprio(0);

        if (pref) loadKf(Kb, kv0 + 128, lq, lg, kf);

        if (domask) {
            #pragma unroll
            for (int sub = 0; sub < 2; ++sub) {
                const int qrow = q0 + sub * 16 + lq;
                #pragma unroll
                for (int n = 0; n < 4; ++n) {
                    const int kvb = kv0 + n * 16 + lg * 4;
                    #pragma unroll
                    for (int r = 0; r < 4; ++r)
                        if (kvb + r > qrow) z[sub][n][r] = -INFINITY;
                }
            }
        }

        // ---- combined defer check (one ballot for both subs) ----
        float mt[2];
        #pragma unroll
        for (int sub = 0; sub < 2; ++sub) {
            float t = -INFINITY;
            #pragma unroll
            for (int n = 0; n < 4; ++n)
                #pragma unroll
                for (int r = 0; r < 4; ++r)
                    t = fmaxf(t, z[sub][n][r]);
            mt[sub] = t;
        }
        const float g = fmaxf(mt[0] - m[0], mt[1] - m[1]);
        const bool skip = __all(g <= DEFER_THR);

        if (!skip) {   // rare: exact full path for both subs
            #pragma unroll
            for (int sub = 0; sub < 2; ++sub) {
                float mf = fmaxf(mt[sub], __shfl_xor(mt[sub], 16));
                mf = fmaxf(mf, __shfl_xor(mf, 32));
                const float mn = fmaxf(m[sub], mf);
                const float sc = exp2f(m[sub] - mn);
                m[sub] = mn;
                lsum[sub] *= sc;
                float scy[4];
                #pragma unroll
                for (int r = 0; r < 4; ++r) scy[r] = __shfl(sc, lg * 4 + r);
                #pragma unroll
                for (int n = 0; n < 4; ++n)
                    #pragma unroll
                    for (int r = 0; r < 4; ++r)
                        y[sub][n][r] *= scy[r];
            }
        }

        // ---- exp2 + cvt_pk + LDS writes for BOTH subs, then reads, then PV ----
        float ps[2] = {0.f, 0.f};
        #pragma unroll
        for (int sub = 0; sub < 2; ++sub) {
            #pragma unroll
            for (int n = 0; n < 4; ++n) {
                float e0 = exp2f(z[sub][n][0] - m[sub]);
                float e1 = exp2f(z[sub][n][1] - m[sub]);
                float e2 = exp2f(z[sub][n][2] - m[sub]);
                float e3 = exp2f(z[sub][n][3] - m[sub]);
                ps[sub] += (e0 + e1) + (e2 + e3);
                uint32_t p0, p1;
                asm("v_cvt_pk_bf16_f32 %0, %1, %2" : "=v"(p0) : "v"(e0), "v"(e1));
                asm("v_cvt_pk_bf16_f32 %0, %1, %2" : "=v"(p1) : "v"(e2), "v"(e3));
                uint2 u; u.x = p0; u.y = p1;
                *(uint2*)&Pl[wv][sub][lq][n * 16 + lg * 4] = u;
            }
        }
        lsum[0] += ps[0];
        lsum[1] += ps[1];

        short8 pa[2][2];
        #pragma unroll
        for (int sub = 0; sub < 2; ++sub) {
            pa[sub][0] = *(short8*)&Pl[wv][sub][lq][lg * 8];
            pa[sub][1] = *(short8*)&Pl[wv][sub][lq][lg * 8 + 32];
        }

        __builtin_amdgcn_s_setprio(1);
        #pragma unroll
        for (int sub = 0; sub < 2; ++sub)
            #pragma unroll
            for (int n = 0; n < 4; ++n) {
                y[sub][n] = __builtin_amdgcn_mfma_f32_16x16x32_bf16(pa[sub][0], vv[2 * n], y[sub][n], 0, 0, 0);
                y[sub][n] = __builtin_amdgcn_mfma_f32_16x16x32_bf16(pa[sub][1], vv[2 * n + 1], y[sub][n], 0, 0, 0);
            }
        __builtin_amdgcn_s_setprio(0);
    };

    if (wv <= qt) {
        int kt = wv;
        for (; kt + 2 <= qt; kt += 2)
            step(kt * 64, false, true);     // steady state: no mask, prefetch K
        step(kt * 64, kt == qt, false);     // final owned tile (mask iff diagonal)
    }

    // ---- reduce per-lane lsum across lg groups (both waves) ----
    float ls[2];
    #pragma unroll
    for (int sub = 0; sub < 2; ++sub) {
        float t = lsum[sub];
        t += __shfl_xor(t, 16);
        t += __shfl_xor(t, 32);
        ls[sub] = t;
    }

    // ---- merge: wave1 posts partials; wave0 combines + writes ----
    if (wv == 1) {
        #pragma unroll
        for (int sub = 0; sub < 2; ++sub) {
            #pragma unroll
            for (int n = 0; n < 4; ++n)
                #pragma unroll
                for (int r = 0; r < 4; ++r)
                    My[sub * 16 + lg * 4 + r][n * 16 + lq] = y[sub][n][r];
            if (lg == 0) Mml[sub * 16 + lq] = make_float2(m[sub], ls[sub]);
        }
    }
    __syncthreads();
    if (wv == 0) {
        #pragma unroll
        for (int sub = 0; sub < 2; ++sub) {
            float2 o = Mml[sub * 16 + lq];
            const float m1 = o.x, l1 = o.y;
            const float mx = fmaxf(m[sub], m1);
            const float w0 = exp2f(m[sub] - mx);
            const float w1 = exp2f(m1 - mx);
            const float inv = 1.0f / (ls[sub] * w0 + l1 * w1);
            const float f0 = w0 * inv, f1 = w1 * inv;
            float f0r[4], f1r[4];
            #pragma unroll
            for (int r = 0; r < 4; ++r) {
                f0r[r] = __shfl(f0, lg * 4 + r);
                f1r[r] = __shfl(f1, lg * 4 + r);
            }
            #pragma unroll
            for (int r = 0; r < 4; ++r) {
                int token = b * 2048 + q0 + sub * 16 + lg * 4 + r;
                uint16_t* yrow = Y + (size_t)token * 1024 + h * 64;
                #pragma unroll
                for (int n = 0; n < 4; ++n) {
                    float val = y[sub][n][r] * f0r[r] +
                                My[sub * 16 + lg * 4 + r][n * 16 + lq] * f1r[r];
                    yrow[n * 16 + lq] = f2bf(val);
                }
            }
        }
    }
}

// ======================= output projection (MFMA, fp32 out) =======================
// out[4096,1024] = Y(bf16) @ Wo(bf16)^T + bo. BK=64 + XCD column affinity.
__global__ __launch_bounds__(256) void gemm_proj(
    const uint16_t* __restrict__ Yin, const uint16_t* __restrict__ W,
    const float* __restrict__ bias, float* __restrict__ out)
{
    __shared__ __align__(16) uint16_t smem[16384];   // 4 x [128][32] = 32 KB
    uint16_t* As0 = smem;
    uint16_t* As1 = smem + 4096;
    uint16_t* Bs0 = smem + 8192;
    uint16_t* Bs1 = smem + 12288;

    const int tid = threadIdx.x;
    const int w = tid >> 6, l = tid & 63;
    const int lq = l & 15, lg = l >> 4;
    const int wm = w >> 1, wn = w & 1;

    const int flat = blockIdx.x + blockIdx.y * 8;
    const int n0 = (flat & 7) * 128;
    const int m0 = (flat >> 3) * 128;

    f32x4 acc[4][4] = {};

    for (int k0 = 0; k0 < 1024; k0 += 64) {
        __syncthreads();
        #pragma unroll
        for (int j = 0; j < 2; ++j) {
            const int c = (j * 4 + w) * 64 + l;
            const size_t ra = (size_t)(m0 + (c >> 2)) * 1024 + k0 + (c & 3) * 8;
            const size_t rb = (size_t)(n0 + (c >> 2)) * 1024 + k0 + (c & 3) * 8;
            load_lds16(Yin + ra,      As0 + (j * 4 + w) * 512);
            load_lds16(Yin + ra + 32, As1 + (j * 4 + w) * 512);
            load_lds16(W + rb,        Bs0 + (j * 4 + w) * 512);
            load_lds16(W + rb + 32,   Bs1 + (j * 4 + w) * 512);
        }
        __syncthreads();
        short8 af[4], bfr[4];
        #pragma unroll
        for (int mi = 0; mi < 4; ++mi)
            af[mi] = *(const short8*)&As0[(wm * 64 + mi * 16 + lq) * 32 + lg * 8];
        #pragma unroll
        for (int ni = 0; ni < 4; ++ni)
            bfr[ni] = *(const short8*)&Bs0[(wn * 64 + ni * 16 + lq) * 32 + lg * 8];
        #pragma unroll
        for (int mi = 0; mi < 4; ++mi)
            #pragma unroll
            for (int ni = 0; ni < 4; ++ni)
                acc[mi][ni] = __builtin_amdgcn_mfma_f32_16x16x32_bf16(
                    af[mi], bfr[ni], acc[mi][ni], 0, 0, 0);
        #pragma unroll
        for (int mi = 0; mi < 4; ++mi)
            af[mi] = *(const short8*)&As1[(wm * 64 + mi * 16 + lq) * 32 + lg * 8];
        #pragma unroll
        for (int ni = 0; ni < 4; ++ni)
            bfr[ni] = *(const short8*)&Bs1[(wn * 64 + ni * 16 + lq) * 32 + lg * 8];
        #pragma unroll
        for (int mi = 0; mi < 4; ++mi)
            #pragma unroll
            for (int ni = 0; ni < 4; ++ni)
                acc[mi][ni] = __builtin_amdgcn_mfma_f32_16x16x32_bf16(
                    af[mi], bfr[ni], acc[mi][ni], 0, 0, 0);
    }

    const int mrow0 = m0 + wm * 64;
    const int ncol0 = n0 + wn * 64;
    float bias4[4];
    #pragma unroll
    for (int ni = 0; ni < 4; ++ni)
        bias4[ni] = bias[ncol0 + ni * 16 + lq];

    #pragma unroll
    for (int mi = 0; mi < 4; ++mi)
        #pragma unroll
        for (int r = 0; r < 4; ++r) {
            const size_t rowoff = (size_t)(mrow0 + mi * 16 + lg * 4 + r) * 1024;
            #pragma unroll
            for (int ni = 0; ni < 4; ++ni)
                out[rowoff + ncol0 + ni * 16 + lq] = acc[mi][ni][r] + bias4[ni];
        }
}

// ======================= launcher =======================

extern "C" void kernel_launch(void* const* d_in, const int* in_sizes, int n_in,
                              void* d_out, int out_size, void* d_ws, size_t ws_size,
                              hipStream_t stream) {
    const float* x    = (const float*)d_in[0];
    // d_in[1] (causal mask) applied structurally.
    const float* Wqkv = (const float*)d_in[2];
    const float* bqkv = (const float*)d_in[3];
    const float* Wo   = (const float*)d_in[4];
    const float* bo   = (const float*)d_in[5];

    const size_t QK = (size_t)BB * HH * NN * SS;  // 4,194,304

    uint16_t* Xb  = (uint16_t*)d_ws;
    uint16_t* Wqb = Xb + XE;
    uint16_t* Wob = Wqb + WQE;
    uint16_t* Qb  = Wob + WOE;
    uint16_t* Kb  = Qb + QK;
    uint16_t* Vt  = Kb + QK;
    uint16_t* Yb  = Vt + QK;

    cvt_all<<<(XE + WQE + WOE) / 8 / 256, 256, 0, stream>>>(x, Wqkv, Wo, Xb);
    gemm_qkv<<<dim3(24, 32), 256, 0, stream>>>(Xb, Wqb, bqkv, Qb, Kb, Vt);
    attn_mfma<<<2048, 128, 0, stream>>>(Qb, Kb, Vt, Yb);
    gemm_proj<<<dim3(8, 32), 256, 0, stream>>>(Yb, Wob, bo, (float*)d_out);
}